// Round 4
// baseline (436.002 us; speedup 1.0000x reference)
//
#include <hip/hip_runtime.h>
#include <hip/hip_bf16.h>
#include <hip/hip_cooperative_groups.h>
#include <math.h>

namespace cg = cooperative_groups;

#define D_    256
#define NSQ   4096
#define NL    2
#define HID_  1024
#define R0_   3969
#define EH_   3906
#define EV_   3906
#define NV_   3844
#define LN_EPS_ 1e-5f
#define CLAMP_  1e-8f
#define TK_    64

typedef float f32x4 __attribute__((ext_vector_type(4)));
typedef __bf16 bf16x8 __attribute__((ext_vector_type(8)));
typedef unsigned short u16x8 __attribute__((ext_vector_type(8)));

__device__ __forceinline__ void gload_lds16(const void* g, void* l) {
    __builtin_amdgcn_global_load_lds(
        (const __attribute__((address_space(1))) void*)g,
        (__attribute__((address_space(3))) void*)l, 16, 0, 0);
}

// =================== templated bf16 MFMA GEMM body, double-buffered ===================
// A [M,K] bf16 row-major; Bt [N,K] bf16. 256 thr = 4 waves.
// outmode: 0 f32 row-major (+resf); 1 bf16 row-major (+resb); 2 bf16 transposed;
//          3 bf16 fragment-packed (V layout for attention)
template<int BM, int BN>
__device__ __forceinline__ void gemm_body(
    const __hip_bfloat16* __restrict__ A, const __hip_bfloat16* __restrict__ Bt,
    const float* __restrict__ bias,
    const float* resf, const __hip_bfloat16* __restrict__ resb,
    void* __restrict__ C, int M, int N, int K, int relu, int outmode,
    int bx, int by)
{
    constexpr int WR  = BM / 64;
    constexpr int WC  = 4 / WR;
    constexpr int WNT = BN / WC;
    constexpr int NF  = WNT / 16;
    constexpr int ACH = BM / 64;
    constexpr int BCH = BN / 64;
    constexpr int ASZ = BM * 32;

    __shared__ __hip_bfloat16 sm[2][(BM + BN) * 32];

    const int t = threadIdx.x;
    const int lane = t & 63, wave = t >> 6;
    const int ln = lane & 15, lg = lane >> 4;
    const int wr = (WR == 1) ? 0 : (wave >> 1);
    const int wc = (WR == 1) ? wave : (wave & 1);
    const int row0 = bx * BM, col0 = by * BN;

    int aoff[ACH], boff[BCH];
    #pragma unroll
    for (int c = 0; c < ACH; ++c) {
        int e = (c * 256 + t) * 8;
        int row = e >> 5, slot = (e >> 3) & 3;
        int kg = slot ^ (row & 3) ^ ((row >> 2) & 3);
        aoff[c] = row * K + kg * 8;
    }
    #pragma unroll
    for (int c = 0; c < BCH; ++c) {
        int e = (c * 256 + t) * 8;
        int row = e >> 5, slot = (e >> 3) & 3;
        int kg = slot ^ (row & 3) ^ ((row >> 2) & 3);
        boff[c] = row * K + kg * 8;
    }
    const int sw = (ln & 3) ^ ((ln >> 2) & 3);

    const __hip_bfloat16* Ab = A + (size_t)row0 * K;
    const __hip_bfloat16* Bb = Bt + (size_t)col0 * K;

    f32x4 acc[4][NF];
    #pragma unroll
    for (int m = 0; m < 4; ++m)
        #pragma unroll
        for (int n = 0; n < NF; ++n) acc[m][n] = f32x4{0.f, 0.f, 0.f, 0.f};

    auto STAGE = [&](int k0, int buf) {
        #pragma unroll
        for (int c = 0; c < ACH; ++c)
            gload_lds16(Ab + k0 + aoff[c], (char*)&sm[buf][0] + (c * 256 + t) * 16);
        #pragma unroll
        for (int c = 0; c < BCH; ++c)
            gload_lds16(Bb + k0 + boff[c], (char*)&sm[buf][ASZ] + (c * 256 + t) * 16);
    };

    STAGE(0, 0);
    __syncthreads();
    int cur = 0;
    for (int k0 = 0; k0 < K; k0 += 32) {
        if (k0 + 32 < K) STAGE(k0 + 32, cur ^ 1);
        bf16x8 af[4], bfr[NF];
        #pragma unroll
        for (int m = 0; m < 4; ++m)
            af[m] = *(const bf16x8*)((const char*)&sm[cur][0] +
                     (size_t)(wr * 64 + m * 16 + ln) * 64 + ((lg ^ sw) << 4));
        #pragma unroll
        for (int n = 0; n < NF; ++n)
            bfr[n] = *(const bf16x8*)((const char*)&sm[cur][ASZ] +
                     (size_t)(wc * WNT + n * 16 + ln) * 64 + ((lg ^ sw) << 4));
        #pragma unroll
        for (int m = 0; m < 4; ++m)
            #pragma unroll
            for (int n = 0; n < NF; ++n)
                acc[m][n] = __builtin_amdgcn_mfma_f32_16x16x32_bf16(
                    af[m], bfr[n], acc[m][n], 0, 0, 0);
        __syncthreads();
        cur ^= 1;
    }

    #pragma unroll
    for (int m = 0; m < 4; ++m) {
        const int rowb = row0 + wr * 64 + m * 16 + lg * 4;
        #pragma unroll
        for (int n = 0; n < NF; ++n) {
            const int col = col0 + wc * WNT + n * 16 + ln;
            const float bv = bias ? bias[col] : 0.f;
            if (outmode == 2) {
                union { ushort4 u4; __hip_bfloat16 h[4]; } pk;
                #pragma unroll
                for (int r = 0; r < 4; ++r) {
                    float v = acc[m][n][r] + bv;
                    if (relu) v = fmaxf(v, 0.f);
                    pk.h[r] = __float2bfloat16(v);
                }
                *(ushort4*)((__hip_bfloat16*)C + (size_t)col * M + rowb) = pk.u4;
            } else if (outmode == 3) {
                union { ushort4 u4; __hip_bfloat16 h[4]; } pk;
                #pragma unroll
                for (int r = 0; r < 4; ++r) {
                    float v = acc[m][n][r] + bv;
                    if (relu) v = fmaxf(v, 0.f);
                    pk.h[r] = __float2bfloat16(v);
                }
                size_t off = ((size_t)((rowb >> 5) * 16 + (col >> 4)) << 9)
                           + (size_t)(((rowb >> 3) & 3) * 16 + (col & 15)) * 8
                           + (rowb & 7);
                *(ushort4*)((__hip_bfloat16*)C + off) = pk.u4;
            } else {
                #pragma unroll
                for (int r = 0; r < 4; ++r) {
                    float v = acc[m][n][r] + bv;
                    if (relu) v = fmaxf(v, 0.f);
                    const size_t idx = (size_t)(rowb + r) * N + col;
                    if (resf) v += resf[idx];
                    if (resb) v += __bfloat162float(resb[idx]);
                    if (outmode == 0) ((float*)C)[idx] = v;
                    else ((__hip_bfloat16*)C)[idx] = __float2bfloat16(v);
                }
            }
        }
    }
}

// ============ fused QK + V projection: grid (64, 6); y<4 -> QK, y>=4 -> V ============
__global__ __launch_bounds__(256) void gemm_qkv(
    const __hip_bfloat16* __restrict__ xb,
    const __hip_bfloat16* __restrict__ wqkt2, const __hip_bfloat16* __restrict__ wvt2,
    const float* __restrict__ bqk2, const float* __restrict__ bv,
    __hip_bfloat16* __restrict__ qkb, __hip_bfloat16* __restrict__ vf, int l)
{
    const __hip_bfloat16* Bt;
    const float* bias;
    void* C;
    int N, outmode, by;
    if (blockIdx.y < 4) {
        Bt = wqkt2 + (size_t)l * 131072; bias = bqk2 + l * 512;
        C = qkb; N = 512; outmode = 1; by = blockIdx.y;
    } else {
        Bt = wvt2 + (size_t)l * 65536; bias = bv + l * D_;
        C = vf; N = D_; outmode = 3; by = blockIdx.y - 4;
    }
    gemm_body<64, 128>(xb, Bt, bias, nullptr, nullptr, C, NSQ, N, D_, 0, outmode,
                       blockIdx.x, by);
}

// ===== cooperative proj GEMM + LayerNorm: 256 blocks x 256 thr =====
// phase 1: y = ctx @ Wd^T + bd + res (f32, 64x64 tiles, bx=b&63, by=b>>6)
// phase 2 (after grid sync): LN over rows; 1024 waves x 4 rows each.
__global__ __launch_bounds__(256) void projln_k(
    const __hip_bfloat16* __restrict__ ctxb, const __hip_bfloat16* __restrict__ wdt,
    const float* __restrict__ bd, const float* resf,
    float* __restrict__ yb,
    const float* __restrict__ g, const float* __restrict__ b,
    float* xo, __hip_bfloat16* __restrict__ xob,
    __hip_bfloat16* __restrict__ feats, int fin)
{
    gemm_body<64, 64>(ctxb, wdt, bd, resf, nullptr, yb, NSQ, D_, D_, 0, 0,
                      (int)(blockIdx.x & 63), (int)(blockIdx.x >> 6));
    cg::this_grid().sync();

    const int lane = threadIdx.x & 63, wave = threadIdx.x >> 6;
    const int gw = blockIdx.x * 4 + wave;          // 1024 waves
    for (int i = 0; i < 4; ++i) {
        const int row = gw * 4 + i;
        float4 v = *(const float4*)(yb + (size_t)row * D_ + lane * 4);
        float s = v.x + v.y + v.z + v.w;
        #pragma unroll
        for (int off = 1; off < 64; off <<= 1) s += __shfl_xor(s, off);
        float mu = s * (1.f / D_);
        float dx = v.x - mu, dy = v.y - mu, dz = v.z - mu, dw = v.w - mu;
        float q = dx * dx + dy * dy + dz * dz + dw * dw;
        #pragma unroll
        for (int off = 1; off < 64; off <<= 1) q += __shfl_xor(q, off);
        float inv = rsqrtf(q * (1.f / D_) + LN_EPS_);
        float4 gg = *(const float4*)(g + lane * 4);
        float4 bb = *(const float4*)(b + lane * 4);
        float4 o;
        o.x = dx * inv * gg.x + bb.x;
        o.y = dy * inv * gg.y + bb.y;
        o.z = dz * inv * gg.z + bb.z;
        o.w = dw * inv * gg.w + bb.w;
        union { ushort4 u4; __hip_bfloat16 h[4]; } pk;
        pk.h[0] = __float2bfloat16(o.x); pk.h[1] = __float2bfloat16(o.y);
        pk.h[2] = __float2bfloat16(o.z); pk.h[3] = __float2bfloat16(o.w);
        if (!fin) {
            *(float4*)(xo + (size_t)row * D_ + lane * 4) = o;
            *(ushort4*)(xob + (size_t)row * D_ + lane * 4) = pk.u4;
        } else {
            const int r = row >> 6, c = row & 63;
            if (r < 63 && c < 63)
                *(ushort4*)(feats + (size_t)(r * 63 + c) * 1024 + lane * 4) = pk.u4;
            if (r < 63 && c > 0)
                *(ushort4*)(feats + (size_t)(r * 63 + c - 1) * 1024 + 256 + lane * 4) = pk.u4;
            if (r > 0 && c < 63)
                *(ushort4*)(feats + (size_t)((r - 1) * 63 + c) * 1024 + 512 + lane * 4) = pk.u4;
            if (r > 0 && c > 0)
                *(ushort4*)(feats + (size_t)((r - 1) * 63 + c - 1) * 1024 + 768 + lane * 4) = pk.u4;
        }
    }
}

// ======= pipelined 128x128 MLP GEMM: 256 thr / 4 waves (64x64 per wave) =======
__global__ __launch_bounds__(256, 2) void gemm_128p(
    const __hip_bfloat16* __restrict__ A, const __hip_bfloat16* __restrict__ Bt,
    const float* __restrict__ bias, const __hip_bfloat16* __restrict__ resb,
    __hip_bfloat16* __restrict__ C, int M, int N, int K, int relu)
{
    __shared__ __hip_bfloat16 sm[4][8192];   // 4 bufs x (A 128x32 | B 128x32) = 64KB

    const int t = threadIdx.x;
    const int lane = t & 63, wave = t >> 6;
    const int ln = lane & 15, lg = lane >> 4;
    const int wr = wave >> 1, wc = wave & 1;
    const int row0 = blockIdx.x * 128, col0 = blockIdx.y * 128;

    int aoff[2];
    #pragma unroll
    for (int c = 0; c < 2; ++c) {
        int e = (c * 256 + t) * 8;
        int row = e >> 5, slot = (e >> 3) & 3;
        int kg = slot ^ (row & 3) ^ ((row >> 2) & 3);
        aoff[c] = row * K + kg * 8;
    }
    const int sw = (ln & 3) ^ ((ln >> 2) & 3);

    const __hip_bfloat16* Ab = A + (size_t)row0 * K;
    const __hip_bfloat16* Bb = Bt + (size_t)col0 * K;

    f32x4 acc[4][4];
    #pragma unroll
    for (int m = 0; m < 4; ++m)
        #pragma unroll
        for (int n = 0; n < 4; ++n) acc[m][n] = f32x4{0.f, 0.f, 0.f, 0.f};

    auto STAGE = [&](int k0, int buf) {
        #pragma unroll
        for (int c = 0; c < 2; ++c) {
            gload_lds16(Ab + k0 + aoff[c], (char*)&sm[buf][0] + (c * 256 + t) * 16);
            gload_lds16(Bb + k0 + aoff[c], (char*)&sm[buf][4096] + (c * 256 + t) * 16);
        }
    };

    const int NT = K >> 5;
    STAGE(0, 0); STAGE(32, 1); STAGE(64, 2);

    for (int tt = 0; tt < NT; ++tt) {
        const int rem = NT - 1 - tt;
        if (rem >= 2)      asm volatile("s_waitcnt vmcnt(8)" ::: "memory");
        else if (rem == 1) asm volatile("s_waitcnt vmcnt(4)" ::: "memory");
        else               asm volatile("s_waitcnt vmcnt(0)" ::: "memory");
        __builtin_amdgcn_sched_barrier(0);
        __builtin_amdgcn_s_barrier();
        if (tt + 3 < NT) STAGE((tt + 3) * 32, (tt + 3) & 3);

        const char* base = (const char*)&sm[tt & 3][0];
        bf16x8 af[4], bfr[4];
        #pragma unroll
        for (int m = 0; m < 4; ++m)
            af[m] = *(const bf16x8*)(base +
                     (size_t)(wr * 64 + m * 16 + ln) * 64 + ((lg ^ sw) << 4));
        #pragma unroll
        for (int n = 0; n < 4; ++n)
            bfr[n] = *(const bf16x8*)(base + 8192 +
                     (size_t)(wc * 64 + n * 16 + ln) * 64 + ((lg ^ sw) << 4));
        #pragma unroll
        for (int m = 0; m < 4; ++m)
            #pragma unroll
            for (int n = 0; n < 4; ++n)
                acc[m][n] = __builtin_amdgcn_mfma_f32_16x16x32_bf16(
                    af[m], bfr[n], acc[m][n], 0, 0, 0);
    }

    #pragma unroll
    for (int m = 0; m < 4; ++m) {
        const int rowb = row0 + wr * 64 + m * 16 + lg * 4;
        #pragma unroll
        for (int n = 0; n < 4; ++n) {
            const int col = col0 + wc * 64 + n * 16 + ln;
            const float bv = bias[col];
            #pragma unroll
            for (int r = 0; r < 4; ++r) {
                float v = acc[m][n][r] + bv;
                if (relu) v = fmaxf(v, 0.f);
                const size_t idx = (size_t)(rowb + r) * N + col;
                if (resb) v += __bfloat162float(resb[idx]);
                C[idx] = __float2bfloat16(v);
            }
        }
    }
}

// ====== fused prep (5700 blocks): castb | owt | attn-wt8 | catbias2 | mlp-wt4 ======
__global__ __launch_bounds__(256) void prep_k(
    const float* __restrict__ node_emb, __hip_bfloat16* __restrict__ xb,
    const float* __restrict__ outw, __hip_bfloat16* __restrict__ outwt,
    const float* __restrict__ Wq, const float* __restrict__ Wk,
    const float* __restrict__ Wv, const float* __restrict__ Wd,
    __hip_bfloat16* __restrict__ wqkt2, __hip_bfloat16* __restrict__ wvt2,
    __hip_bfloat16* __restrict__ wdt2,
    const float* __restrict__ bq, const float* __restrict__ bk,
    float* __restrict__ bqk2,
    const float* __restrict__ M0, const float* __restrict__ M1,
    const float* __restrict__ M2, const float* __restrict__ M3,
    __hip_bfloat16* __restrict__ T0, __hip_bfloat16* __restrict__ T1,
    __hip_bfloat16* __restrict__ T2, __hip_bfloat16* __restrict__ T3,
    float* __restrict__ outp)
{
    __shared__ float tile[32][33];
    const int b = blockIdx.x, t = threadIdx.x;
    if (b == 0 && t < 2) outp[t] = 0.f;
    if (b < 1024) {
        int p = b * 256 + t;
        float4 v = *(const float4*)(node_emb + (size_t)p * 4);
        union { ushort4 u4; __hip_bfloat16 h[4]; } pk;
        pk.h[0] = __float2bfloat16(v.x); pk.h[1] = __float2bfloat16(v.y);
        pk.h[2] = __float2bfloat16(v.z); pk.h[3] = __float2bfloat16(v.w);
        *(ushort4*)(xb + (size_t)p * 4) = pk.u4;
    } else if (b < 1088) {
        int i = (b - 1024) * 256 + t;
        int n = i >> 10, k = i & 1023;
        outwt[i] = __float2bfloat16(outw[k * 16 + n]);
    } else if (b < 1600) {
        int idx = b - 1088;
        int z = idx >> 6, bx = (idx >> 3) & 7, by = idx & 7;
        int l = z >> 2, w = z & 3;
        const float* W = (w == 0 ? Wq : w == 1 ? Wk : w == 2 ? Wv : Wd) + (size_t)l * 65536;
        __hip_bfloat16* Wt = w == 0 ? wqkt2 + (size_t)l * 131072
                           : w == 1 ? wqkt2 + (size_t)l * 131072 + 65536
                           : w == 2 ? wvt2 + (size_t)l * 65536
                                    : wdt2 + (size_t)l * 65536;
        int k0 = bx * 32, n0 = by * 32;
        int r = t >> 3, c4 = (t & 7) * 4;
        float4 v = *(const float4*)(W + (size_t)(k0 + r) * 256 + n0 + c4);
        tile[r][c4 + 0] = v.x; tile[r][c4 + 1] = v.y;
        tile[r][c4 + 2] = v.z; tile[r][c4 + 3] = v.w;
        __syncthreads();
        union { ushort4 u4; __hip_bfloat16 h[4]; } pk;
        #pragma unroll
        for (int i = 0; i < 4; ++i) pk.h[i] = __float2bfloat16(tile[c4 + i][r]);
        *(ushort4*)(Wt + (size_t)(n0 + r) * 256 + k0 + c4) = pk.u4;
    } else if (b < 1604) {
        int idx = (b - 1600) * 256 + t;
        int l = idx >> 9, j = idx & 511;
        bqk2[idx] = j < 256 ? bq[l * 256 + j] : bk[l * 256 + j - 256];
    } else {
        int idx = b - 1604;
        int z = idx >> 10, rem = idx & 1023;
        const float* W = z == 0 ? M0 : z == 1 ? M1 : z == 2 ? M2 : M3;
        __hip_bfloat16* Wt = z == 0 ? T0 : z == 1 ? T1 : z == 2 ? T2 : T3;
        int k0 = (rem >> 5) * 32, n0 = (rem & 31) * 32;
        int r = t >> 3, c4 = (t & 7) * 4;
        float4 v = *(const float4*)(W + (size_t)(k0 + r) * 1024 + n0 + c4);
        tile[r][c4 + 0] = v.x; tile[r][c4 + 1] = v.y;
        tile[r][c4 + 2] = v.z; tile[r][c4 + 3] = v.w;
        __syncthreads();
        union { ushort4 u4; __hip_bfloat16 h[4]; } pk;
        #pragma unroll
        for (int i = 0; i < 4; ++i) pk.h[i] = __float2bfloat16(tile[c4 + i][r]);
        *(ushort4*)(Wt + (size_t)(n0 + r) * 1024 + k0 + c4) = pk.u4;
    }
}

// ==== cooperative flash attention + combine: 8 waves, TK=64, 1 block/CU ====
// phase 1: split-K attention -> po/pm/pl; grid.sync(); phase 2: combine -> ctx.
__global__ __launch_bounds__(512, 2) void attn_fused(
    const __hip_bfloat16* __restrict__ qk, const __hip_bfloat16* vf,
    __hip_bfloat16* __restrict__ po, float* __restrict__ pm, float* __restrict__ pl,
    __hip_bfloat16* ctx)
{
    constexpr int KS = 8;
    constexpr int KRANGE = NSQ / KS;
    constexpr int NT = KRANGE / TK_;
    constexpr int VOFF = 65536;
    constexpr int POFF = 98304;
    const int t = threadIdx.x;
    const int wave = t >> 6, lane = t & 63;
    const int ln = lane & 15, lg = lane >> 4;
    const int q0 = blockIdx.x * 128 + wave * 16;
    const int ks = blockIdx.y;
    const int k0 = ks * KRANGE;

    __shared__ __align__(16) char smem[116736];

    bf16x8 qa[8];
    #pragma unroll
    for (int s = 0; s < 8; ++s)
        qa[s] = *(const bf16x8*)(qk + (size_t)(q0 + ln) * 512 + s * 32 + lg * 8);

    int srcoff[4];
    #pragma unroll
    for (int c = 0; c < 4; ++c) {
        int row = c * 16 + (t >> 5);
        int g = (t & 31) ^ ((row & 15) << 1);
        srcoff[c] = row * 512 + 256 + g * 8;
    }
    int rb[8];
    #pragma unroll
    for (int s8 = 0; s8 < 8; ++s8)
        rb[s8] = ln * 512 + (((s8 * 4 + lg) ^ (ln << 1)) << 4);

    f32x4 o[16];
    #pragma unroll
    for (int nt = 0; nt < 16; ++nt) o[nt] = f32x4{0.f, 0.f, 0.f, 0.f};
    float rm = -1e30f, rl = 0.f;

    {
        const __hip_bfloat16* src = qk + (size_t)k0 * 512;
        #pragma unroll
        for (int c = 0; c < 4; ++c)
            gload_lds16(src + srcoff[c], smem + c * 8192 + t * 16);
    }
    __syncthreads();

    for (int it = 0; it < NT; ++it) {
        const int cur = it & 1;
        {
            const __hip_bfloat16* vsrc = vf + ((size_t)((k0 + it * TK_) >> 5) << 13);
            #pragma unroll
            for (int c = 0; c < 4; ++c) {
                int idx = c * 512 + t;
                gload_lds16(vsrc + (size_t)idx * 8, smem + VOFF + idx * 16);
            }
        }
        {
            const int itn = (it + 1 < NT) ? it + 1 : it;
            const __hip_bfloat16* src = qk + (size_t)(k0 + itn * TK_) * 512;
            #pragma unroll
            for (int c = 0; c < 4; ++c)
                gload_lds16(src + srcoff[c], smem + (cur ^ 1) * 32768 + c * 8192 + t * 16);
        }
        const char* kbase = smem + cur * 32768;
        f32x4 s4[4];
        #pragma unroll
        for (int nt = 0; nt < 4; ++nt) {
            f32x4 acc = {0.f, 0.f, 0.f, 0.f};
            #pragma unroll
            for (int s8 = 0; s8 < 8; ++s8) {
                bf16x8 kb = *(const bf16x8*)(kbase + nt * 8192 + rb[s8]);
                acc = __builtin_amdgcn_mfma_f32_16x16x32_bf16(kb, qa[s8], acc, 0, 0, 0);
            }
            s4[nt] = acc;
        }
        float mx = -1e30f;
        #pragma unroll
        for (int nt = 0; nt < 4; ++nt)
            #pragma unroll
            for (int r = 0; r < 4; ++r) mx = fmaxf(mx, s4[nt][r]);
        mx = fmaxf(mx, __shfl_xor(mx, 16));
        mx = fmaxf(mx, __shfl_xor(mx, 32));
        float sc = 1.f;
        if (__any(mx > rm + 8.f)) {
            float mnew = fmaxf(rm, mx);
            sc = __expf(rm - mnew);
            rm = mnew;
            float scr[4];
            #pragma unroll
            for (int r = 0; r < 4; ++r) scr[r] = __shfl(sc, lg * 4 + r);
            #pragma unroll
            for (int nt = 0; nt < 16; ++nt)
                #pragma unroll
                for (int r = 0; r < 4; ++r) o[nt][r] *= scr[r];
        }
        float rs = 0.f;
        #pragma unroll
        for (int nt = 0; nt < 4; ++nt)
            #pragma unroll
            for (int r = 0; r < 4; ++r) {
                float p = __expf(s4[nt][r] - rm);
                s4[nt][r] = p;
                rs += p;
            }
        rs += __shfl_xor(rs, 16);
        rs += __shfl_xor(rs, 32);
        rl = rl * sc + rs;
        char* prow = smem + POFF + wave * 2304 + ln * 144;
        #pragma unroll
        for (int nt = 0; nt < 4; ++nt) {
            union { ushort4 u4; __hip_bfloat16 h[4]; } pk;
            #pragma unroll
            for (int r = 0; r < 4; ++r) pk.h[r] = __float2bfloat16(s4[nt][r]);
            *(ushort4*)(prow + nt * 32 + lg * 8) = pk.u4;
        }
        asm volatile("s_waitcnt lgkmcnt(0)" ::: "memory");
        __builtin_amdgcn_sched_barrier(0);
        bf16x8 pa0 = *(const bf16x8*)(prow + lg * 16);
        bf16x8 pa1 = *(const bf16x8*)(prow + 64 + lg * 16);
        asm volatile("s_waitcnt vmcnt(4)" ::: "memory");
        __builtin_amdgcn_sched_barrier(0);
        __builtin_amdgcn_s_barrier();
        const char* vl = smem + VOFF;
        #pragma unroll
        for (int ntd = 0; ntd < 16; ++ntd) {
            bf16x8 vb0 = *(const bf16x8*)(vl + ntd * 1024 + lane * 16);
            bf16x8 vb1 = *(const bf16x8*)(vl + 16384 + ntd * 1024 + lane * 16);
            o[ntd] = __builtin_amdgcn_mfma_f32_16x16x32_bf16(pa0, vb0, o[ntd], 0, 0, 0);
            o[ntd] = __builtin_amdgcn_mfma_f32_16x16x32_bf16(pa1, vb1, o[ntd], 0, 0, 0);
        }
        __syncthreads();
    }
    unsigned short* ob = (unsigned short*)(smem + wave * 8448);
    #pragma unroll
    for (int nt = 0; nt < 16; ++nt)
        #pragma unroll
        for (int r = 0; r < 4; ++r) {
            __hip_bfloat16 h = __float2bfloat16(o[nt][r]);
            ob[(lg * 4 + r) * 264 + nt * 16 + ln] = *(unsigned short*)&h;
        }
    asm volatile("s_waitcnt lgkmcnt(0)" ::: "memory");
    __builtin_amdgcn_sched_barrier(0);
    unsigned short* pob = (unsigned short*)po;
    #pragma unroll
    for (int i = 0; i < 8; ++i) {
        int f = i * 64 + lane;
        int row = f >> 5, dc = f & 31;
        u16x8 vv = *(const u16x8*)(ob + row * 264 + dc * 8);
        *(u16x8*)(pob + ((size_t)ks * NSQ + q0 + row) * D_ + dc * 8) = vv;
    }
    if (lane < 16) {
        pm[ks * NSQ + q0 + lane] = rm;
        pl[ks * NSQ + q0 + lane] = rl;
    }

    // ---------- phase 2: combine (after all splits done) ----------
    cg::this_grid().sync();
    {
        const int bid = blockIdx.y * 32 + blockIdx.x;   // gridDim = (32, 8)
        const int idx8 = bid * 512 + t;                 // 131072 units total
        const int row = idx8 >> 5;
        float m2[KS], ms = -1e30f;
        #pragma unroll
        for (int s = 0; s < KS; ++s) { m2[s] = pm[s * NSQ + row]; ms = fmaxf(ms, m2[s]); }
        float l2 = 0.f, w2[KS];
        #pragma unroll
        for (int s = 0; s < KS; ++s) {
            w2[s] = __expf(m2[s] - ms);
            l2 += w2[s] * pl[s * NSQ + row];
        }
        const float inv = 1.f / l2;
        float num[8];
        #pragma unroll
        for (int j = 0; j < 8; ++j) num[j] = 0.f;
        #pragma unroll
        for (int s = 0; s < KS; ++s) {
            u16x8 v = *(const u16x8*)((const unsigned short*)po +
                        (size_t)s * (NSQ * D_) + (size_t)idx8 * 8);
            #pragma unroll
            for (int j = 0; j < 8; ++j) {
                union { float f; unsigned u; } cv;
                cv.u = (unsigned)v[j] << 16;
                num[j] += w2[s] * cv.f;
            }
        }
        union { u16x8 u8; __hip_bfloat16 h[8]; } pk;
        #pragma unroll
        for (int j = 0; j < 8; ++j) pk.h[j] = __float2bfloat16(num[j] * inv);
        *(u16x8*)(ctx + (size_t)idx8 * 8) = pk.u8;
    }
}

// ===== cooperative tail: logits/softmax/belief/R0 -> edges -> nodes (64 blocks) =====
__global__ __launch_bounds__(256) void tail_k(
    const __hip_bfloat16* __restrict__ A, const __hip_bfloat16* __restrict__ Bt,
    const float* __restrict__ bias, const float* __restrict__ lphi0,
    float* __restrict__ beliefs,
    const float* __restrict__ lphih, const float* __restrict__ lphiv,
    float* __restrict__ hbel, float* __restrict__ vbel,
    const float* __restrict__ lphi2, float* __restrict__ out)
{
    const int t = threadIdx.x, lane = t & 63, wave = t >> 6;
    const int ln = lane & 15, lg = lane >> 4;
    {   // phase 1: per-block 64 rows of logits -> softmax -> beliefs + R0 energy
        const int r0 = blockIdx.x * 64 + wave * 16;
        f32x4 acc = {0.f, 0.f, 0.f, 0.f};
        for (int k0 = 0; k0 < HID_; k0 += 32) {
            bf16x8 a = *(const bf16x8*)(A + (size_t)(r0 + ln) * HID_ + k0 + lg * 8);
            bf16x8 b = *(const bf16x8*)(Bt + (size_t)ln * HID_ + k0 + lg * 8);
            acc = __builtin_amdgcn_mfma_f32_16x16x32_bf16(a, b, acc, 0, 0, 0);
        }
        float e = 0.f;
        #pragma unroll
        for (int r = 0; r < 4; ++r) {
            const int row = r0 + lg * 4 + r;
            float v = acc[r] + bias[ln];
            float mx = v;
            mx = fmaxf(mx, __shfl_xor(mx, 1));
            mx = fmaxf(mx, __shfl_xor(mx, 2));
            mx = fmaxf(mx, __shfl_xor(mx, 4));
            mx = fmaxf(mx, __shfl_xor(mx, 8));
            float ex = __expf(v - mx);
            float s = ex;
            s += __shfl_xor(s, 1);
            s += __shfl_xor(s, 2);
            s += __shfl_xor(s, 4);
            s += __shfl_xor(s, 8);
            if (row < R0_) {
                float bb = ex / s;
                beliefs[(size_t)row * 16 + ln] = bb;
                float bc = fmaxf(bb, CLAMP_);
                e += bc * (logf(bc) - lphi0[(size_t)row * 16 + ln]);
            }
        }
        #pragma unroll
        for (int off = 32; off; off >>= 1) e += __shfl_down(e, off);
        if (lane == 0) atomicAdd(&out[0], e);
    }
    cg::this_grid().sync();
    {   // phase 2: edges (thread space: [0,EH_) horizontal, [8192,8192+EV_) vertical)
        const int gg = blockIdx.x * 256 + t;
        float el = 0.f, ml = 0.f;
        if (gg < EH_) {
            const int e = gg;
            const float* bA = beliefs + (size_t)e * 16;
            const float* bB = beliefs + (size_t)(e + 63) * 16;
            float s0[4] = {0,0,0,0}, s1[4] = {0,0,0,0};
            #pragma unroll
            for (int ab = 0; ab < 4; ++ab)
                #pragma unroll
                for (int cd = 0; cd < 4; ++cd) {
                    s0[cd] += bA[ab * 4 + cd];
                    s1[ab] += bB[ab * 4 + cd];
                }
            #pragma unroll
            for (int z = 0; z < 4; ++z) {
                float hb = 0.5f * (s0[z] + s1[z]);
                hbel[e * 4 + z] = hb;
                float d0 = s0[z] - hb, d1 = s1[z] - hb;
                ml += d0 * d0 + d1 * d1;
                float bc = fmaxf(hb, CLAMP_);
                el -= bc * (logf(bc) - lphih[e * 4 + z]);
            }
        } else if (gg >= 8192 && gg < 8192 + EV_) {
            const int e = gg - 8192;
            int r = e / 62, c = e % 62 + 1;
            const float* bL = beliefs + (size_t)(r * 63 + c - 1) * 16;
            const float* bR = beliefs + (size_t)(r * 63 + c) * 16;
            float s0[4] = {0,0,0,0}, s1[4] = {0,0,0,0};
            #pragma unroll
            for (int a = 0; a < 2; ++a)
                #pragma unroll
                for (int bq = 0; bq < 2; ++bq)
                    #pragma unroll
                    for (int c2 = 0; c2 < 2; ++c2)
                        #pragma unroll
                        for (int d = 0; d < 2; ++d) {
                            int idx = a * 8 + bq * 4 + c2 * 2 + d;
                            s0[bq * 2 + d]  += bL[idx];
                            s1[a * 2 + c2] += bR[idx];
                        }
            #pragma unroll
            for (int z = 0; z < 4; ++z) {
                float vb = 0.5f * (s0[z] + s1[z]);
                vbel[e * 4 + z] = vb;
                float d0 = s0[z] - vb, d1 = s1[z] - vb;
                ml += d0 * d0 + d1 * d1;
                float bc = fmaxf(vb, CLAMP_);
                el -= bc * (logf(bc) - lphiv[e * 4 + z]);
            }
        }
        #pragma unroll
        for (int off = 32; off; off >>= 1) { el += __shfl_down(el, off); ml += __shfl_down(ml, off); }
        if (lane == 0) { atomicAdd(&out[0], el); atomicAdd(&out[1], ml); }
    }
    cg::this_grid().sync();
    {   // phase 3: interior nodes
        const int vtx = blockIdx.x * 256 + t;
        float el = 0.f, ml = 0.f;
        if (vtx < NV_) {
            int hl = (vtx / 62) * 63 + (vtx % 62);
            int hr = hl + 1;
            int vu = vtx;
            int vd = vtx + 62;
            float n0[2], n1[2], n2[2], n3[2];
            #pragma unroll
            for (int z = 0; z < 2; ++z) {
                n0[z] = hbel[hl * 4 + z] + hbel[hl * 4 + 2 + z];
                n1[z] = hbel[hr * 4 + z * 2] + hbel[hr * 4 + z * 2 + 1];
                n2[z] = vbel[vu * 4 + z] + vbel[vu * 4 + 2 + z];
                n3[z] = vbel[vd * 4 + z * 2] + vbel[vd * 4 + z * 2 + 1];
            }
            #pragma unroll
            for (int z = 0; z < 2; ++z) {
                float nb = 0.25f * (n0[z] + n1[z] + n2[z] + n3[z]);
                float d0 = n0[z] - nb, d1 = n1[z] - nb, d2 = n2[z] - nb, d3 = n3[z] - nb;
                ml += d0 * d0 + d1 * d1 + d2 * d2 + d3 * d3;
                float bc = fmaxf(nb, CLAMP_);
                el += bc * (logf(bc) - lphi2[vtx * 2 + z]);
            }
        }
        #pragma unroll
        for (int off = 32; off; off >>= 1) { el += __shfl_down(el, off); ml += __shfl_down(ml, off); }
        if (lane == 0) { atomicAdd(&out[0], el); atomicAdd(&out[1], ml); }
    }
}

// =======================================================================================
extern "C" void kernel_launch(void* const* d_in, const int* in_sizes, int n_in,
                              void* d_out, int out_size, void* d_ws, size_t ws_size,
                              hipStream_t stream)
{
    (void)in_sizes; (void)n_in; (void)out_size; (void)ws_size;
    const float* node_emb = (const float*)d_in[0];
    const float* Wq  = (const float*)d_in[1];
    const float* bq  = (const float*)d_in[2];
    const float* Wk  = (const float*)d_in[3];
    const float* bk  = (const float*)d_in[4];
    const float* Wv  = (const float*)d_in[5];
    const float* bv  = (const float*)d_in[6];
    const float* Wd  = (const float*)d_in[7];
    const float* bd  = (const float*)d_in[8];
    const float* lng = (const float*)d_in[9];
    const float* lnb = (const float*)d_in[10];
    const float* r1w1 = (const float*)d_in[11];
    const float* r1b1 = (const float*)d_in[12];
    const float* r1w2 = (const float*)d_in[13];
    const float* r1b2 = (const float*)d_in[14];
    const float* r2w1 = (const float*)d_in[15];
    const float* r2b1 = (const float*)d_in[16];
    const float* r2w2 = (const float*)d_in[17];
    const float* r2b2 = (const float*)d_in[18];
    const float* outw = (const float*)d_in[19];
    const float* outb = (const float*)d_in[20];
    const float* lphi0 = (const float*)d_in[21];
    const float* lphih = (const float*)d_in[22];
    const float* lphiv = (const float*)d_in[23];
    const float* lphi2 = (const float*)d_in[24];

    float* ws = (float*)d_ws;
    // persistent block (units: floats)
    float* x      = ws;                          // 1,048,576
    __hip_bfloat16* xb = (__hip_bfloat16*)(ws + 1048576);
    float* belief = ws + 1638400;
    float* hbel   = ws + 1703936;
    float* vbel   = ws + 1720320;
    __hip_bfloat16* outwt = (__hip_bfloat16*)(ws + 1736704);
    float* arena  = ws + 1744896;

    // phase A (attention) layout inside arena (float offsets)
    __hip_bfloat16* wqkt2 = (__hip_bfloat16*)(arena);                // [2][512][256]
    __hip_bfloat16* wvt2  = (__hip_bfloat16*)(arena + 131072);       // [2][256][256]
    __hip_bfloat16* wdt2  = (__hip_bfloat16*)(arena + 196608);       // [2][256][256]
    float* bqk2 = arena + 262144;                                    // [2][512]
    __hip_bfloat16* qkb = (__hip_bfloat16*)(arena + 263168);         // [4096][512]
    __hip_bfloat16* vf  = (__hip_bfloat16*)(arena + 1311744);        // packed V (2MB)
    __hip_bfloat16* ctxb = vf;                                       // alias: vf dead post-attn
    float* yb = arena + 1836032;
    float* pm = arena + 2884608;                                     // [8][4096]
    float* pl = arena + 2950144;
    __hip_bfloat16* po = (__hip_bfloat16*)(arena + 3015680);         // 8M bf16 (KSPLIT=8)

    // phase B: feats + MLP weights OUTSIDE arena; hA/hB reuse dead attention arena.
    __hip_bfloat16* feats = (__hip_bfloat16*)(ws + 8954880);         // [4096][1024] bf16
    __hip_bfloat16* w1t = (__hip_bfloat16*)(ws + 11052032);
    __hip_bfloat16* w2t = (__hip_bfloat16*)(ws + 11576320);
    __hip_bfloat16* w3t = (__hip_bfloat16*)(ws + 12100608);
    __hip_bfloat16* w4t = (__hip_bfloat16*)(ws + 12624896);
    __hip_bfloat16* hA  = (__hip_bfloat16*)(arena);
    __hip_bfloat16* hB  = (__hip_bfloat16*)(arena + 2097152);

    float* outp = (float*)d_out;
    dim3 blk(256);
    prep_k<<<dim3(5700), blk, 0, stream>>>(node_emb, xb, outw, outwt,
                                           Wq, Wk, Wv, Wd, wqkt2, wvt2, wdt2,
                                           bq, bk, bqk2,
                                           r1w1, r1w2, r2w1, r2w2,
                                           w1t, w2t, w3t, w4t, outp);

    for (int l = 0; l < NL; ++l) {
        gemm_qkv<<<dim3(64, 6), blk, 0, stream>>>(xb, wqkt2, wvt2, bqk2, bv,
                                                  qkb, vf, l);
        {
            void* aArgs[] = {(void*)&qkb, (void*)&vf, (void*)&po,
                             (void*)&pm, (void*)&pl, (void*)&ctxb};
            hipLaunchCooperativeKernel((const void*)attn_fused,
                                       dim3(NSQ / 128, 8), dim3(512), aArgs, 0, stream);
        }
        {
            const __hip_bfloat16* wdtl = wdt2 + (size_t)l * 65536;
            const float* bdl  = bd + l * D_;
            const float* resl = (l == 0) ? node_emb : x;
            const float* lngl = lng + l * D_;
            const float* lnbl = lnb + l * D_;
            int finl = l;
            void* pArgs[] = {(void*)&ctxb, (void*)&wdtl, (void*)&bdl, (void*)&resl,
                             (void*)&yb, (void*)&lngl, (void*)&lnbl,
                             (void*)&x, (void*)&xb, (void*)&feats, (void*)&finl};
            hipLaunchCooperativeKernel((const void*)projln_k,
                                       dim3(256), dim3(256), pArgs, 0, stream);
        }
    }

    dim3 gM(NSQ / 128, HID_ / 128);   // (32, 8) = 256 blocks, 1/CU
    gemm_128p<<<gM, blk, 0, stream>>>(feats, w1t, r1b1, nullptr,
                                      hA, NSQ, HID_, HID_, 1);
    gemm_128p<<<gM, blk, 0, stream>>>(hA, w2t, r1b2, feats,
                                      hB, NSQ, HID_, HID_, 1);
    gemm_128p<<<gM, blk, 0, stream>>>(hB, w3t, r2b1, nullptr,
                                      hA, NSQ, HID_, HID_, 1);
    gemm_128p<<<gM, blk, 0, stream>>>(hA, w4t, r2b2, hB,
                                      feats, NSQ, HID_, HID_, 1);

    {
        void* tArgs[] = {(void*)&feats, (void*)&outwt, (void*)&outb, (void*)&lphi0,
                         (void*)&belief, (void*)&lphih, (void*)&lphiv,
                         (void*)&hbel, (void*)&vbel, (void*)&lphi2, (void*)&outp};
        hipLaunchCooperativeKernel((const void*)tail_k,
                                   dim3(64), dim3(256), tArgs, 0, stream);
    }
}

// Round 6
// 222.786 us; speedup vs baseline: 1.9570x; 1.9570x over previous
//
#include <hip/hip_runtime.h>
#include <hip/hip_bf16.h>
#include <math.h>

#define D_    256
#define NSQ   4096
#define NL    2
#define HID_  1024
#define R0_   3969
#define EH_   3906
#define EV_   3906
#define NV_   3844
#define LN_EPS_ 1e-5f
#define CLAMP_  1e-8f
#define TK_    64

typedef float f32x4 __attribute__((ext_vector_type(4)));
typedef __bf16 bf16x8 __attribute__((ext_vector_type(8)));
typedef unsigned short u16x8 __attribute__((ext_vector_type(8)));

__device__ __forceinline__ void gload_lds16(const void* g, void* l) {
    __builtin_amdgcn_global_load_lds(
        (const __attribute__((address_space(1))) void*)g,
        (__attribute__((address_space(3))) void*)l, 16, 0, 0);
}

// =================== templated bf16 MFMA GEMM body, double-buffered ===================
// A [M,K] bf16 row-major; Bt [N,K] bf16. 256 thr = 4 waves.
// outmode: 0 f32 row-major (+resf); 1 bf16 row-major (+resb); 2 bf16 transposed;
//          3 bf16 fragment-packed (V layout for attention)
template<int BM, int BN>
__device__ __forceinline__ void gemm_body(
    const __hip_bfloat16* __restrict__ A, const __hip_bfloat16* __restrict__ Bt,
    const float* __restrict__ bias,
    const float* __restrict__ resf, const __hip_bfloat16* __restrict__ resb,
    void* __restrict__ C, int M, int N, int K, int relu, int outmode,
    int bx, int by)
{
    constexpr int WR  = BM / 64;
    constexpr int WC  = 4 / WR;
    constexpr int WNT = BN / WC;
    constexpr int NF  = WNT / 16;
    constexpr int ACH = BM / 64;
    constexpr int BCH = BN / 64;
    constexpr int ASZ = BM * 32;

    __shared__ __hip_bfloat16 sm[2][(BM + BN) * 32];

    const int t = threadIdx.x;
    const int lane = t & 63, wave = t >> 6;
    const int ln = lane & 15, lg = lane >> 4;
    const int wr = (WR == 1) ? 0 : (wave >> 1);
    const int wc = (WR == 1) ? wave : (wave & 1);
    const int row0 = bx * BM, col0 = by * BN;

    int aoff[ACH], boff[BCH];
    #pragma unroll
    for (int c = 0; c < ACH; ++c) {
        int e = (c * 256 + t) * 8;
        int row = e >> 5, slot = (e >> 3) & 3;
        int kg = slot ^ (row & 3) ^ ((row >> 2) & 3);
        aoff[c] = row * K + kg * 8;
    }
    #pragma unroll
    for (int c = 0; c < BCH; ++c) {
        int e = (c * 256 + t) * 8;
        int row = e >> 5, slot = (e >> 3) & 3;
        int kg = slot ^ (row & 3) ^ ((row >> 2) & 3);
        boff[c] = row * K + kg * 8;
    }
    const int sw = (ln & 3) ^ ((ln >> 2) & 3);

    const __hip_bfloat16* Ab = A + (size_t)row0 * K;
    const __hip_bfloat16* Bb = Bt + (size_t)col0 * K;

    f32x4 acc[4][NF];
    #pragma unroll
    for (int m = 0; m < 4; ++m)
        #pragma unroll
        for (int n = 0; n < NF; ++n) acc[m][n] = f32x4{0.f, 0.f, 0.f, 0.f};

    auto STAGE = [&](int k0, int buf) {
        #pragma unroll
        for (int c = 0; c < ACH; ++c)
            gload_lds16(Ab + k0 + aoff[c], (char*)&sm[buf][0] + (c * 256 + t) * 16);
        #pragma unroll
        for (int c = 0; c < BCH; ++c)
            gload_lds16(Bb + k0 + boff[c], (char*)&sm[buf][ASZ] + (c * 256 + t) * 16);
    };

    STAGE(0, 0);
    __syncthreads();
    int cur = 0;
    for (int k0 = 0; k0 < K; k0 += 32) {
        if (k0 + 32 < K) STAGE(k0 + 32, cur ^ 1);
        bf16x8 af[4], bfr[NF];
        #pragma unroll
        for (int m = 0; m < 4; ++m)
            af[m] = *(const bf16x8*)((const char*)&sm[cur][0] +
                     (size_t)(wr * 64 + m * 16 + ln) * 64 + ((lg ^ sw) << 4));
        #pragma unroll
        for (int n = 0; n < NF; ++n)
            bfr[n] = *(const bf16x8*)((const char*)&sm[cur][ASZ] +
                     (size_t)(wc * WNT + n * 16 + ln) * 64 + ((lg ^ sw) << 4));
        #pragma unroll
        for (int m = 0; m < 4; ++m)
            #pragma unroll
            for (int n = 0; n < NF; ++n)
                acc[m][n] = __builtin_amdgcn_mfma_f32_16x16x32_bf16(
                    af[m], bfr[n], acc[m][n], 0, 0, 0);
        __syncthreads();
        cur ^= 1;
    }

    #pragma unroll
    for (int m = 0; m < 4; ++m) {
        const int rowb = row0 + wr * 64 + m * 16 + lg * 4;
        #pragma unroll
        for (int n = 0; n < NF; ++n) {
            const int col = col0 + wc * WNT + n * 16 + ln;
            const float bv = bias ? bias[col] : 0.f;
            if (outmode == 2) {
                union { ushort4 u4; __hip_bfloat16 h[4]; } pk;
                #pragma unroll
                for (int r = 0; r < 4; ++r) {
                    float v = acc[m][n][r] + bv;
                    if (relu) v = fmaxf(v, 0.f);
                    pk.h[r] = __float2bfloat16(v);
                }
                *(ushort4*)((__hip_bfloat16*)C + (size_t)col * M + rowb) = pk.u4;
            } else if (outmode == 3) {
                union { ushort4 u4; __hip_bfloat16 h[4]; } pk;
                #pragma unroll
                for (int r = 0; r < 4; ++r) {
                    float v = acc[m][n][r] + bv;
                    if (relu) v = fmaxf(v, 0.f);
                    pk.h[r] = __float2bfloat16(v);
                }
                size_t off = ((size_t)((rowb >> 5) * 16 + (col >> 4)) << 9)
                           + (size_t)(((rowb >> 3) & 3) * 16 + (col & 15)) * 8
                           + (rowb & 7);
                *(ushort4*)((__hip_bfloat16*)C + off) = pk.u4;
            } else {
                #pragma unroll
                for (int r = 0; r < 4; ++r) {
                    float v = acc[m][n][r] + bv;
                    if (relu) v = fmaxf(v, 0.f);
                    const size_t idx = (size_t)(rowb + r) * N + col;
                    if (resf) v += resf[idx];
                    if (resb) v += __bfloat162float(resb[idx]);
                    if (outmode == 0) ((float*)C)[idx] = v;
                    else ((__hip_bfloat16*)C)[idx] = __float2bfloat16(v);
                }
            }
        }
    }
}

template<int BM, int BN>
__global__ __launch_bounds__(256) void gemm_t(
    const __hip_bfloat16* __restrict__ A, const __hip_bfloat16* __restrict__ Bt,
    const float* __restrict__ bias,
    const float* __restrict__ resf, const __hip_bfloat16* __restrict__ resb,
    void* __restrict__ C, int M, int N, int K, int relu, int outmode)
{
    gemm_body<BM, BN>(A, Bt, bias, resf, resb, C, M, N, K, relu, outmode,
                      blockIdx.x, blockIdx.y);
}

// ============ fused QK + V projection: grid (64, 6); y<4 -> QK, y>=4 -> V ============
__global__ __launch_bounds__(256) void gemm_qkv(
    const __hip_bfloat16* __restrict__ xb,
    const __hip_bfloat16* __restrict__ wqkt2, const __hip_bfloat16* __restrict__ wvt2,
    const float* __restrict__ bqk2, const float* __restrict__ bv,
    __hip_bfloat16* __restrict__ qkb, __hip_bfloat16* __restrict__ vf, int l)
{
    const __hip_bfloat16* Bt;
    const float* bias;
    void* C;
    int N, outmode, by;
    if (blockIdx.y < 4) {
        Bt = wqkt2 + (size_t)l * 131072; bias = bqk2 + l * 512;
        C = qkb; N = 512; outmode = 1; by = blockIdx.y;
    } else {
        Bt = wvt2 + (size_t)l * 65536; bias = bv + l * D_;
        C = vf; N = D_; outmode = 3; by = blockIdx.y - 4;
    }
    gemm_body<64, 128>(xb, Bt, bias, nullptr, nullptr, C, NSQ, N, D_, 0, outmode,
                       blockIdx.x, by);
}

// ======= pipelined 128x128 MLP GEMM, BK=64: 256 thr / 4 waves (64x64 per wave) =======
// 3 LDS buffers (96KB), 2-deep prefetch, ONE barrier + counted vmcnt per 64-K step.
// Per buffer: A tile [128 rows][8 slots x 16B] at +0 (16KB), B tile at +16KB.
// Swizzle: LDS[row][s] = global slot s^(row&7); read s = (kh*4+lg)^(row&7).
__global__ __launch_bounds__(256, 2) void gemm_128p(
    const __hip_bfloat16* __restrict__ A, const __hip_bfloat16* __restrict__ Bt,
    const float* __restrict__ bias, const __hip_bfloat16* __restrict__ resb,
    __hip_bfloat16* __restrict__ C, int M, int N, int K, int relu)
{
    __shared__ __hip_bfloat16 sm[3][16384];   // 3 bufs x (A 128x64 | B 128x64) = 96KB

    const int t = threadIdx.x;
    const int lane = t & 63, wave = t >> 6;
    const int ln = lane & 15, lg = lane >> 4;
    const int wr = wave >> 1, wc = wave & 1;
    const int row0 = blockIdx.x * 128, col0 = blockIdx.y * 128;

    // staging: 4 chunks of 16B per thread per matrix; pre-swizzled global source
    int aoff[4];
    #pragma unroll
    for (int c = 0; c < 4; ++c) {
        int e = c * 256 + t;           // 0..1023, 16B each
        int row = e >> 3, slot = e & 7;
        int kg = slot ^ (row & 7);
        aoff[c] = row * K + kg * 8;
    }

    const __hip_bfloat16* Ab = A + (size_t)row0 * K;
    const __hip_bfloat16* Bb = Bt + (size_t)col0 * K;

    f32x4 acc[4][4];
    #pragma unroll
    for (int m = 0; m < 4; ++m)
        #pragma unroll
        for (int n = 0; n < 4; ++n) acc[m][n] = f32x4{0.f, 0.f, 0.f, 0.f};

    auto STAGE = [&](int tile, int buf) {
        const int k0 = tile * 64;
        #pragma unroll
        for (int c = 0; c < 4; ++c) {
            gload_lds16(Ab + k0 + aoff[c], (char*)&sm[buf][0] + (c * 256 + t) * 16);
            gload_lds16(Bb + k0 + aoff[c], (char*)&sm[buf][8192] + (c * 256 + t) * 16);
        }
    };

    const int NT = K >> 6;    // 16 for K=1024
    STAGE(0, 0); STAGE(1, 1);

    int buf = 0;
    for (int tt = 0; tt < NT; ++tt) {
        const int rem = NT - 1 - tt;
        // tile tt landed; tile tt+1 (8 loads) stays in flight
        if (rem >= 1) asm volatile("s_waitcnt vmcnt(8)" ::: "memory");
        else          asm volatile("s_waitcnt vmcnt(0)" ::: "memory");
        __builtin_amdgcn_sched_barrier(0);
        __builtin_amdgcn_s_barrier();
        // prefetch tile tt+2 into buffer (tt+2)%3 == the buffer last read at iter tt-1
        if (tt + 2 < NT) STAGE(tt + 2, (buf + 2 >= 3) ? buf - 1 : buf + 2);

        const char* base = (const char*)&sm[buf][0];
        #pragma unroll
        for (int kh = 0; kh < 2; ++kh) {
            bf16x8 af[4], bfr[4];
            #pragma unroll
            for (int m = 0; m < 4; ++m) {
                const int row = wr * 64 + m * 16 + ln;
                af[m] = *(const bf16x8*)(base + row * 128 +
                         (((kh * 4 + lg) ^ (row & 7)) << 4));
            }
            #pragma unroll
            for (int n = 0; n < 4; ++n) {
                const int row = wc * 64 + n * 16 + ln;
                bfr[n] = *(const bf16x8*)(base + 16384 + row * 128 +
                          (((kh * 4 + lg) ^ (row & 7)) << 4));
            }
            #pragma unroll
            for (int m = 0; m < 4; ++m)
                #pragma unroll
                for (int n = 0; n < 4; ++n)
                    acc[m][n] = __builtin_amdgcn_mfma_f32_16x16x32_bf16(
                        af[m], bfr[n], acc[m][n], 0, 0, 0);
        }
        buf = (buf + 1 >= 3) ? 0 : buf + 1;
    }

    #pragma unroll
    for (int m = 0; m < 4; ++m) {
        const int rowb = row0 + wr * 64 + m * 16 + lg * 4;
        #pragma unroll
        for (int n = 0; n < 4; ++n) {
            const int col = col0 + wc * 64 + n * 16 + ln;
            const float bv = bias[col];
            #pragma unroll
            for (int r = 0; r < 4; ++r) {
                float v = acc[m][n][r] + bv;
                if (relu) v = fmaxf(v, 0.f);
                const size_t idx = (size_t)(rowb + r) * N + col;
                if (resb) v += __bfloat162float(resb[idx]);
                C[idx] = __float2bfloat16(v);
            }
        }
    }
}

// ========= small-N GEMM fused with softmax+belief+R0 energy (N=16) =========
__global__ __launch_bounds__(256) void gemm_n16b(
    const __hip_bfloat16* __restrict__ A, const __hip_bfloat16* __restrict__ Bt,
    const float* __restrict__ bias, const float* __restrict__ lphi0,
    float* __restrict__ beliefs, float* __restrict__ out, int M, int K)
{
    const int t = threadIdx.x, lane = t & 63, wave = t >> 6;
    const int ln = lane & 15, lg = lane >> 4;
    const int r0 = blockIdx.x * 64 + wave * 16;
    f32x4 acc = {0.f, 0.f, 0.f, 0.f};
    for (int k0 = 0; k0 < K; k0 += 32) {
        bf16x8 a = *(const bf16x8*)(A + (size_t)(r0 + ln) * K + k0 + lg * 8);
        bf16x8 b = *(const bf16x8*)(Bt + (size_t)ln * K + k0 + lg * 8);
        acc = __builtin_amdgcn_mfma_f32_16x16x32_bf16(a, b, acc, 0, 0, 0);
    }
    float e = 0.f;
    #pragma unroll
    for (int r = 0; r < 4; ++r) {
        const int row = r0 + lg * 4 + r;
        float v = acc[r] + bias[ln];
        float mx = v;
        mx = fmaxf(mx, __shfl_xor(mx, 1));
        mx = fmaxf(mx, __shfl_xor(mx, 2));
        mx = fmaxf(mx, __shfl_xor(mx, 4));
        mx = fmaxf(mx, __shfl_xor(mx, 8));
        float ex = __expf(v - mx);
        float s = ex;
        s += __shfl_xor(s, 1);
        s += __shfl_xor(s, 2);
        s += __shfl_xor(s, 4);
        s += __shfl_xor(s, 8);
        if (row < R0_) {
            float bb = ex / s;
            beliefs[(size_t)row * 16 + ln] = bb;
            float bc = fmaxf(bb, CLAMP_);
            e += bc * (logf(bc) - lphi0[(size_t)row * 16 + ln]);
        }
    }
    #pragma unroll
    for (int off = 32; off; off >>= 1) e += __shfl_down(e, off);
    if (lane == 0) atomicAdd(&out[0], e);
}

// ====== fused prep (5700 blocks): castb | owt | attn-wt8 | catbias2 | mlp-wt4 ======
// also zeroes d_out (stream-ordered before any atomic consumer)
__global__ __launch_bounds__(256) void prep_k(
    const float* __restrict__ node_emb, __hip_bfloat16* __restrict__ xb,
    const float* __restrict__ outw, __hip_bfloat16* __restrict__ outwt,
    const float* __restrict__ Wq, const float* __restrict__ Wk,
    const float* __restrict__ Wv, const float* __restrict__ Wd,
    __hip_bfloat16* __restrict__ wqkt2, __hip_bfloat16* __restrict__ wvt2,
    __hip_bfloat16* __restrict__ wdt2,
    const float* __restrict__ bq, const float* __restrict__ bk,
    float* __restrict__ bqk2,
    const float* __restrict__ M0, const float* __restrict__ M1,
    const float* __restrict__ M2, const float* __restrict__ M3,
    __hip_bfloat16* __restrict__ T0, __hip_bfloat16* __restrict__ T1,
    __hip_bfloat16* __restrict__ T2, __hip_bfloat16* __restrict__ T3,
    float* __restrict__ outp)
{
    __shared__ float tile[32][33];
    const int b = blockIdx.x, t = threadIdx.x;
    if (b == 0 && t < 2) outp[t] = 0.f;
    if (b < 1024) {
        int p = b * 256 + t;
        float4 v = *(const float4*)(node_emb + (size_t)p * 4);
        union { ushort4 u4; __hip_bfloat16 h[4]; } pk;
        pk.h[0] = __float2bfloat16(v.x); pk.h[1] = __float2bfloat16(v.y);
        pk.h[2] = __float2bfloat16(v.z); pk.h[3] = __float2bfloat16(v.w);
        *(ushort4*)(xb + (size_t)p * 4) = pk.u4;
    } else if (b < 1088) {
        int i = (b - 1024) * 256 + t;
        int n = i >> 10, k = i & 1023;
        outwt[i] = __float2bfloat16(outw[k * 16 + n]);
    } else if (b < 1600) {
        int idx = b - 1088;
        int z = idx >> 6, bx = (idx >> 3) & 7, by = idx & 7;
        int l = z >> 2, w = z & 3;
        const float* W = (w == 0 ? Wq : w == 1 ? Wk : w == 2 ? Wv : Wd) + (size_t)l * 65536;
        __hip_bfloat16* Wt = w == 0 ? wqkt2 + (size_t)l * 131072
                           : w == 1 ? wqkt2 + (size_t)l * 131072 + 65536
                           : w == 2 ? wvt2 + (size_t)l * 65536
                                    : wdt2 + (size_t)l * 65536;
        int k0 = bx * 32, n0 = by * 32;
        int r = t >> 3, c4 = (t & 7) * 4;
        float4 v = *(const float4*)(W + (size_t)(k0 + r) * 256 + n0 + c4);
        tile[r][c4 + 0] = v.x; tile[r][c4 + 1] = v.y;
        tile[r][c4 + 2] = v.z; tile[r][c4 + 3] = v.w;
        __syncthreads();
        union { ushort4 u4; __hip_bfloat16 h[4]; } pk;
        #pragma unroll
        for (int i = 0; i < 4; ++i) pk.h[i] = __float2bfloat16(tile[c4 + i][r]);
        *(ushort4*)(Wt + (size_t)(n0 + r) * 256 + k0 + c4) = pk.u4;
    } else if (b < 1604) {
        int idx = (b - 1600) * 256 + t;
        int l = idx >> 9, j = idx & 511;
        bqk2[idx] = j < 256 ? bq[l * 256 + j] : bk[l * 256 + j - 256];
    } else {
        int idx = b - 1604;
        int z = idx >> 10, rem = idx & 1023;
        const float* W = z == 0 ? M0 : z == 1 ? M1 : z == 2 ? M2 : M3;
        __hip_bfloat16* Wt = z == 0 ? T0 : z == 1 ? T1 : z == 2 ? T2 : T3;
        int k0 = (rem >> 5) * 32, n0 = (rem & 31) * 32;
        int r = t >> 3, c4 = (t & 7) * 4;
        float4 v = *(const float4*)(W + (size_t)(k0 + r) * 1024 + n0 + c4);
        tile[r][c4 + 0] = v.x; tile[r][c4 + 1] = v.y;
        tile[r][c4 + 2] = v.z; tile[r][c4 + 3] = v.w;
        __syncthreads();
        union { ushort4 u4; __hip_bfloat16 h[4]; } pk;
        #pragma unroll
        for (int i = 0; i < 4; ++i) pk.h[i] = __float2bfloat16(tile[c4 + i][r]);
        *(ushort4*)(Wt + (size_t)(n0 + r) * 1024 + k0 + c4) = pk.u4;
    }
}

// ============ flash attention: 8 waves, TK=64, counted vmcnt =============
template<int KS>
__global__ __launch_bounds__(512, 2) void attn_mfma_t(
    const __hip_bfloat16* __restrict__ qk, const __hip_bfloat16* __restrict__ vf,
    __hip_bfloat16* __restrict__ po, float* __restrict__ pm, float* __restrict__ pl)
{
    constexpr int KRANGE = NSQ / KS;
    constexpr int NT = KRANGE / TK_;
    constexpr int VOFF = 65536;
    constexpr int POFF = 98304;
    const int t = threadIdx.x;
    const int wave = t >> 6, lane = t & 63;
    const int ln = lane & 15, lg = lane >> 4;
    const int q0 = blockIdx.x * 128 + wave * 16;
    const int ks = blockIdx.y;
    const int k0 = ks * KRANGE;

    __shared__ __align__(16) char smem[116736];

    bf16x8 qa[8];
    #pragma unroll
    for (int s = 0; s < 8; ++s)
        qa[s] = *(const bf16x8*)(qk + (size_t)(q0 + ln) * 512 + s * 32 + lg * 8);

    int srcoff[4];
    #pragma unroll
    for (int c = 0; c < 4; ++c) {
        int row = c * 16 + (t >> 5);
        int g = (t & 31) ^ ((row & 15) << 1);
        srcoff[c] = row * 512 + 256 + g * 8;
    }
    int rb[8];
    #pragma unroll
    for (int s8 = 0; s8 < 8; ++s8)
        rb[s8] = ln * 512 + (((s8 * 4 + lg) ^ (ln << 1)) << 4);

    f32x4 o[16];
    #pragma unroll
    for (int nt = 0; nt < 16; ++nt) o[nt] = f32x4{0.f, 0.f, 0.f, 0.f};
    float rm = -1e30f, rl = 0.f;

    {
        const __hip_bfloat16* src = qk + (size_t)k0 * 512;
        #pragma unroll
        for (int c = 0; c < 4; ++c)
            gload_lds16(src + srcoff[c], smem + c * 8192 + t * 16);
    }
    __syncthreads();

    for (int it = 0; it < NT; ++it) {
        const int cur = it & 1;
        {
            const __hip_bfloat16* vsrc = vf + ((size_t)((k0 + it * TK_) >> 5) << 13);
            #pragma unroll
            for (int c = 0; c < 4; ++c) {
                int idx = c * 512 + t;
                gload_lds16(vsrc + (size_t)idx * 8, smem + VOFF + idx * 16);
            }
        }
        {
            const int itn = (it + 1 < NT) ? it + 1 : it;
            const __hip_bfloat16* src = qk + (size_t)(k0 + itn * TK_) * 512;
            #pragma unroll
            for (int c = 0; c < 4; ++c)
                gload_lds16(src + srcoff[c], smem + (cur ^ 1) * 32768 + c * 8192 + t * 16);
        }
        const char* kbase = smem + cur * 32768;
        f32x4 s4[4];
        #pragma unroll
        for (int nt = 0; nt < 4; ++nt) {
            f32x4 acc = {0.f, 0.f, 0.f, 0.f};
            #pragma unroll
            for (int s8 = 0; s8 < 8; ++s8) {
                bf16x8 kb = *(const bf16x8*)(kbase + nt * 8192 + rb[s8]);
                acc = __builtin_amdgcn_mfma_f32_16x16x32_bf16(kb, qa[s8], acc, 0, 0, 0);
            }
            s4[nt] = acc;
        }
        float mx = -1e30f;
        #pragma unroll
        for (int nt = 0; nt < 4; ++nt)
            #pragma unroll
            for (int r = 0; r < 4; ++r) mx = fmaxf(mx, s4[nt][r]);
        mx = fmaxf(mx, __shfl_xor(mx, 16));
        mx = fmaxf(mx, __shfl_xor(mx, 32));
        float sc = 1.f;
        if (__any(mx > rm + 8.f)) {
            float mnew = fmaxf(rm, mx);
            sc = __expf(rm - mnew);
            rm = mnew;
            float scr[4];
            #pragma unroll
            for (int r = 0; r < 4; ++r) scr[r] = __shfl(sc, lg * 4 + r);
            #pragma unroll
            for (int nt = 0; nt < 16; ++nt)
                #pragma unroll
                for (int r = 0; r < 4; ++r) o[nt][r] *= scr[r];
        }
        float rs = 0.f;
        #pragma unroll
        for (int nt = 0; nt < 4; ++nt)
            #pragma unroll
            for (int r = 0; r < 4; ++r) {
                float p = __expf(s4[nt][r] - rm);
                s4[nt][r] = p;
                rs += p;
            }
        rs += __shfl_xor(rs, 16);
        rs += __shfl_xor(rs, 32);
        rl = rl * sc + rs;
        char* prow = smem + POFF + wave * 2304 + ln * 144;
        #pragma unroll
        for (int nt = 0; nt < 4; ++nt) {
            union { ushort4 u4; __hip_bfloat16 h[4]; } pk;
            #pragma unroll
            for (int r = 0; r < 4; ++r) pk.h[r] = __float2bfloat16(s4[nt][r]);
            *(ushort4*)(prow + nt * 32 + lg * 8) = pk.u4;
        }
        asm volatile("s_waitcnt lgkmcnt(0)" ::: "memory");
        __builtin_amdgcn_sched_barrier(0);
        bf16x8 pa0 = *(const bf16x8*)(prow + lg * 16);
        bf16x8 pa1 = *(const bf16x8*)(prow + 64 + lg * 16);
        asm volatile("s_waitcnt vmcnt(4)" ::: "memory");
        __builtin_amdgcn_sched_barrier(0);
        __builtin_amdgcn_s_barrier();
        const char* vl = smem + VOFF;
        #pragma unroll
        for (int ntd = 0; ntd < 16; ++ntd) {
            bf16x8 vb0 = *(const bf16x8*)(vl + ntd * 1024 + lane * 16);
            bf16x8 vb1 = *(const bf16x8*)(vl + 16384 + ntd * 1024 + lane * 16);
            o[ntd] = __builtin_amdgcn_mfma_f32_16x16x32_bf16(pa0, vb0, o[ntd], 0, 0, 0);
            o[ntd] = __builtin_amdgcn_mfma_f32_16x16x32_bf16(pa1, vb1, o[ntd], 0, 0, 0);
        }
        __syncthreads();
    }
    unsigned short* ob = (unsigned short*)(smem + wave * 8448);
    #pragma unroll
    for (int nt = 0; nt < 16; ++nt)
        #pragma unroll
        for (int r = 0; r < 4; ++r) {
            __hip_bfloat16 h = __float2bfloat16(o[nt][r]);
            ob[(lg * 4 + r) * 264 + nt * 16 + ln] = *(unsigned short*)&h;
        }
    asm volatile("s_waitcnt lgkmcnt(0)" ::: "memory");
    __builtin_amdgcn_sched_barrier(0);
    unsigned short* pob = (unsigned short*)po;
    #pragma unroll
    for (int i = 0; i < 8; ++i) {
        int f = i * 64 + lane;
        int row = f >> 5, dc = f & 31;
        u16x8 vv = *(const u16x8*)(ob + row * 264 + dc * 8);
        *(u16x8*)(pob + ((size_t)ks * NSQ + q0 + row) * D_ + dc * 8) = vv;
    }
    if (lane < 16) {
        pm[ks * NSQ + q0 + lane] = rm;
        pl[ks * NSQ + q0 + lane] = rl;
    }
}

// ============ combine: vectorized u16x8, 8 elems/thread, grid 512 ============
template<int KS>
__global__ __launch_bounds__(256) void attn_combine_t(
    const __hip_bfloat16* __restrict__ po, const float* __restrict__ pm,
    const float* __restrict__ pl, __hip_bfloat16* __restrict__ ctx)
{
    const int idx8 = blockIdx.x * 256 + threadIdx.x;   // unit of 8 elems
    const int row = idx8 >> 5;
    float m[KS], ms = -1e30f;
    #pragma unroll
    for (int s = 0; s < KS; ++s) { m[s] = pm[s * NSQ + row]; ms = fmaxf(ms, m[s]); }
    float l = 0.f, w[KS];
    #pragma unroll
    for (int s = 0; s < KS; ++s) {
        w[s] = __expf(m[s] - ms);
        l += w[s] * pl[s * NSQ + row];
    }
    const float inv = 1.f / l;
    float num[8];
    #pragma unroll
    for (int j = 0; j < 8; ++j) num[j] = 0.f;
    #pragma unroll
    for (int s = 0; s < KS; ++s) {
        u16x8 v = *(const u16x8*)(po + (size_t)s * (NSQ * D_) + (size_t)idx8 * 8);
        #pragma unroll
        for (int j = 0; j < 8; ++j) {
            union { float f; unsigned u; } cv;
            cv.u = (unsigned)v[j] << 16;
            num[j] += w[s] * cv.f;
        }
    }
    union { u16x8 u8; __hip_bfloat16 h[8]; } pk;
    #pragma unroll
    for (int j = 0; j < 8; ++j) pk.h[j] = __float2bfloat16(num[j] * inv);
    *(u16x8*)(ctx + (size_t)idx8 * 8) = pk.u8;
}

// ====== LayerNorm: wave-per-row; final layer scatters feats via reverse r0 map ======
__global__ __launch_bounds__(256) void ln_f32(
    const float* __restrict__ y, const float* __restrict__ g,
    const float* __restrict__ b, float* __restrict__ xo,
    __hip_bfloat16* __restrict__ xob, __hip_bfloat16* __restrict__ feats, int fin)
{
    const int lane = threadIdx.x & 63, wave = threadIdx.x >> 6;
    const int row = blockIdx.x * 4 + wave;
    float4 v = *(const float4*)(y + (size_t)row * D_ + lane * 4);
    float s = v.x + v.y + v.z + v.w;
    #pragma unroll
    for (int off = 1; off < 64; off <<= 1) s += __shfl_xor(s, off);
    float mu = s * (1.f / D_);
    float dx = v.x - mu, dy = v.y - mu, dz = v.z - mu, dw = v.w - mu;
    float q = dx * dx + dy * dy + dz * dz + dw * dw;
    #pragma unroll
    for (int off = 1; off < 64; off <<= 1) q += __shfl_xor(q, off);
    float inv = rsqrtf(q * (1.f / D_) + LN_EPS_);
    float4 gg = *(const float4*)(g + lane * 4);
    float4 bb = *(const float4*)(b + lane * 4);
    float4 o;
    o.x = dx * inv * gg.x + bb.x;
    o.y = dy * inv * gg.y + bb.y;
    o.z = dz * inv * gg.z + bb.z;
    o.w = dw * inv * gg.w + bb.w;
    union { ushort4 u4; __hip_bfloat16 h[4]; } pk;
    pk.h[0] = __float2bfloat16(o.x); pk.h[1] = __float2bfloat16(o.y);
    pk.h[2] = __float2bfloat16(o.z); pk.h[3] = __float2bfloat16(o.w);
    if (!fin) {
        *(float4*)(xo + (size_t)row * D_ + lane * 4) = o;
        *(ushort4*)(xob + (size_t)row * D_ + lane * 4) = pk.u4;
    } else {
        const int r = row >> 6, c = row & 63;
        if (r < 63 && c < 63)
            *(ushort4*)(feats + (size_t)(r * 63 + c) * 1024 + lane * 4) = pk.u4;
        if (r < 63 && c > 0)
            *(ushort4*)(feats + (size_t)(r * 63 + c - 1) * 1024 + 256 + lane * 4) = pk.u4;
        if (r > 0 && c < 63)
            *(ushort4*)(feats + (size_t)((r - 1) * 63 + c) * 1024 + 512 + lane * 4) = pk.u4;
        if (r > 0 && c > 0)
            *(ushort4*)(feats + (size_t)((r - 1) * 63 + c - 1) * 1024 + 768 + lane * 4) = pk.u4;
    }
}

// =================== fused interior edges (y=0: horizontal, y=1: vertical) ============
__global__ __launch_bounds__(256) void edges_k(
    const float* __restrict__ beliefs, const float* __restrict__ lphih,
    const float* __restrict__ lphiv, float* __restrict__ hbel,
    float* __restrict__ vbel, float* __restrict__ out)
{
    int e = blockIdx.x * 256 + threadIdx.x;
    float el = 0.f, ml = 0.f;
    if (blockIdx.y == 0) {
        if (e < EH_) {
            const float* bA = beliefs + (size_t)e * 16;
            const float* bB = beliefs + (size_t)(e + 63) * 16;
            float s0[4] = {0,0,0,0}, s1[4] = {0,0,0,0};
            #pragma unroll
            for (int ab = 0; ab < 4; ++ab)
                #pragma unroll
                for (int cd = 0; cd < 4; ++cd) {
                    s0[cd] += bA[ab * 4 + cd];
                    s1[ab] += bB[ab * 4 + cd];
                }
            #pragma unroll
            for (int z = 0; z < 4; ++z) {
                float hb = 0.5f * (s0[z] + s1[z]);
                hbel[e * 4 + z] = hb;
                float d0 = s0[z] - hb, d1 = s1[z] - hb;
                ml += d0 * d0 + d1 * d1;
                float bc = fmaxf(hb, CLAMP_);
                el -= bc * (logf(bc) - lphih[e * 4 + z]);
            }
        }
    } else {
        if (e < EV_) {
            int r = e / 62, c = e % 62 + 1;
            const float* bL = beliefs + (size_t)(r * 63 + c - 1) * 16;
            const float* bR = beliefs + (size_t)(r * 63 + c) * 16;
            float s0[4] = {0,0,0,0}, s1[4] = {0,0,0,0};
            #pragma unroll
            for (int a = 0; a < 2; ++a)
                #pragma unroll
                for (int bq = 0; bq < 2; ++bq)
                    #pragma unroll
                    for (int c2 = 0; c2 < 2; ++c2)
                        #pragma unroll
                        for (int d = 0; d < 2; ++d) {
                            int idx = a * 8 + bq * 4 + c2 * 2 + d;
                            s0[bq * 2 + d]  += bL[idx];
                            s1[a * 2 + c2] += bR[idx];
                        }
            #pragma unroll
            for (int z = 0; z < 4; ++z) {
                float vb = 0.5f * (s0[z] + s1[z]);
                vbel[e * 4 + z] = vb;
                float d0 = s0[z] - vb, d1 = s1[z] - vb;
                ml += d0 * d0 + d1 * d1;
                float bc = fmaxf(vb, CLAMP_);
                el -= bc * (logf(bc) - lphiv[e * 4 + z]);
            }
        }
    }
    for (int off = 32; off; off >>= 1) { el += __shfl_down(el, off); ml += __shfl_down(ml, off); }
    if ((threadIdx.x & 63) == 0) { atomicAdd(&out[0], el); atomicAdd(&out[1], ml); }
}

// =================== interior nodes ===================
__global__ __launch_bounds__(256) void node_k(
    const float* __restrict__ hbel, const float* __restrict__ vbel,
    const float* __restrict__ lphi2, float* __restrict__ out)
{
    int vtx = blockIdx.x * 256 + threadIdx.x;
    float el = 0.f, ml = 0.f;
    if (vtx < NV_) {
        int hl = (vtx / 62) * 63 + (vtx % 62);
        int hr = hl + 1;
        int vu = vtx;
        int vd = vtx + 62;
        float n0[2], n1[2], n2[2], n3[2];
        #pragma unroll
        for (int z = 0; z < 2; ++z) {
            n0[z] = hbel[hl * 4 + z] + hbel[hl * 4 + 2 + z];
            n1[z] = hbel[hr * 4 + z * 2] + hbel[hr * 4 + z * 2 + 1];
            n2[z] = vbel[vu * 4 + z] + vbel[vu * 4 + 2 + z];
            n3[z] = vbel[vd * 4 + z * 2] + vbel[vd * 4 + z * 2 + 1];
        }
        #pragma unroll
        for (int z = 0; z < 2; ++z) {
            float nb = 0.25f * (n0[z] + n1[z] + n2[z] + n3[z]);
            float d0 = n0[z] - nb, d1 = n1[z] - nb, d2 = n2[z] - nb, d3 = n3[z] - nb;
            ml += d0 * d0 + d1 * d1 + d2 * d2 + d3 * d3;
            float bc = fmaxf(nb, CLAMP_);
            el += bc * (logf(bc) - lphi2[vtx * 2 + z]);
        }
    }
    for (int off = 32; off; off >>= 1) { el += __shfl_down(el, off); ml += __shfl_down(ml, off); }
    if ((threadIdx.x & 63) == 0) { atomicAdd(&out[0], el); atomicAdd(&out[1], ml); }
}

// =======================================================================================
extern "C" void kernel_launch(void* const* d_in, const int* in_sizes, int n_in,
                              void* d_out, int out_size, void* d_ws, size_t ws_size,
                              hipStream_t stream)
{
    (void)in_sizes; (void)n_in; (void)out_size; (void)ws_size;
    const float* node_emb = (const float*)d_in[0];
    const float* Wq  = (const float*)d_in[1];
    const float* bq  = (const float*)d_in[2];
    const float* Wk  = (const float*)d_in[3];
    const float* bk  = (const float*)d_in[4];
    const float* Wv  = (const float*)d_in[5];
    const float* bv  = (const float*)d_in[6];
    const float* Wd  = (const float*)d_in[7];
    const float* bd  = (const float*)d_in[8];
    const float* lng = (const float*)d_in[9];
    const float* lnb = (const float*)d_in[10];
    const float* r1w1 = (const float*)d_in[11];
    const float* r1b1 = (const float*)d_in[12];
    const float* r1w2 = (const float*)d_in[13];
    const float* r1b2 = (const float*)d_in[14];
    const float* r2w1 = (const float*)d_in[15];
    const float* r2b1 = (const float*)d_in[16];
    const float* r2w2 = (const float*)d_in[17];
    const float* r2b2 = (const float*)d_in[18];
    const float* outw = (const float*)d_in[19];
    const float* outb = (const float*)d_in[20];
    const float* lphi0 = (const float*)d_in[21];
    const float* lphih = (const float*)d_in[22];
    const float* lphiv = (const float*)d_in[23];
    const float* lphi2 = (const float*)d_in[24];

    float* ws = (float*)d_ws;
    // persistent block (units: floats)
    float* x      = ws;                          // 1,048,576
    __hip_bfloat16* xb = (__hip_bfloat16*)(ws + 1048576);
    float* belief = ws + 1638400;
    float* hbel   = ws + 1703936;
    float* vbel   = ws + 1720320;
    __hip_bfloat16* outwt = (__hip_bfloat16*)(ws + 1736704);
    float* arena  = ws + 1744896;

    // phase A (attention) layout inside arena (float offsets)
    __hip_bfloat16* wqkt2 = (__hip_bfloat16*)(arena);                // [2][512][256]
    __hip_bfloat16* wvt2  = (__hip_bfloat16*)(arena + 131072);       // [2][256][256]
    __hip_bfloat16* wdt2  = (__hip_bfloat16*)(arena + 196608);       // [2][256][256]
    float* bqk2 = arena + 262144;                                    // [2][512]
    __hip_bfloat16* qkb = (__hip_bfloat16*)(arena + 263168);         // [4096][512]
    __hip_bfloat16* vf  = (__hip_bfloat16*)(arena + 1311744);        // packed V (2MB)
    __hip_bfloat16* ctxb = vf;                                       // alias: vf dead post-attn
    float* yb = arena + 1836032;
    float* pm = arena + 2884608;                                     // [8][4096]
    float* pl = arena + 2950144;
    __hip_bfloat16* po = (__hip_bfloat16*)(arena + 3015680);         // 8M bf16 (KSPLIT=8)

    // phase B: feats + MLP weights OUTSIDE arena; hA/hB reuse dead attention arena.
    __hip_bfloat16* feats = (__hip_bfloat16*)(ws + 8954880);         // [4096][1024] bf16
    __hip_bfloat16* w1t = (__hip_bfloat16*)(ws + 11052032);
    __hip_bfloat16* w2t = (__hip_bfloat16*)(ws + 11576320);
    __hip_bfloat16* w3t = (__hip_bfloat16*)(ws + 12100608);
    __hip_bfloat16* w4t = (__hip_bfloat16*)(ws + 12624896);
    __hip_bfloat16* hA  = (__hip_bfloat16*)(arena);
    __hip_bfloat16* hB  = (__hip_bfloat16*)(arena + 2097152);

    float* outp = (float*)d_out;
    dim3 blk(256);
    dim3 blk512(512);
    prep_k<<<dim3(5700), blk, 0, stream>>>(node_emb, xb, outw, outwt,
                                           Wq, Wk, Wv, Wd, wqkt2, wvt2, wdt2,
                                           bq, bk, bqk2,
                                           r1w1, r1w2, r2w1, r2w2,
                                           w1t, w2t, w3t, w4t, outp);

    for (int l = 0; l < NL; ++l) {
        gemm_qkv<<<dim3(64, 6), blk, 0, stream>>>(xb, wqkt2, wvt2, bqk2, bv,
                                                  qkb, vf, l);
        attn_mfma_t<8><<<dim3(NSQ / 128, 8), blk512, 0, stream>>>(qkb, vf, po, pm, pl);
        attn_combine_t<8><<<dim3(NSQ * D_ / 2048), blk, 0, stream>>>(po, pm, pl, ctxb);
        gemm_t<64, 64><<<dim3(NSQ / 64, D_ / 64), blk, 0, stream>>>(
            ctxb, wdt2 + (size_t)l * 65536, bd + l * D_,
            (l == 0 ? node_emb : x), nullptr, yb, NSQ, D_, D_, 0, 0);
        ln_f32<<<dim3(NSQ / 4), blk, 0, stream>>>(yb, lng + l * D_, lnb + l * D_,
                                                  x, xb, feats, l);
    }

    dim3 gM(NSQ / 128, HID_ / 128);   // (32, 8) = 256 blocks, 1/CU
    gemm_128p<<<gM, blk, 0, stream>>>(feats, w1t, r1b1, nullptr,
                                      hA, NSQ, HID_, HID_, 1);
    gemm_128p<<<gM, blk, 0, stream>>>(hA, w2t, r1b2, feats,
                                      hB, NSQ, HID_, HID_, 1);
    gemm_128p<<<gM, blk, 0, stream>>>(hB, w3t, r2b1, nullptr,
                                      hA, NSQ, HID_, HID_, 1);
    gemm_128p<<<gM, blk, 0, stream>>>(hA, w4t, r2b2, hB,
                                      feats, NSQ, HID_, HID_, 1);

    gemm_n16b<<<dim3(NSQ / 64), blk, 0, stream>>>(feats, outwt, outb, lphi0,
                                                  belief, outp, NSQ, HID_);
    edges_k<<<dim3((EH_ + 255) / 256, 2), blk, 0, stream>>>(belief, lphih, lphiv,
                                                            hbel, vbel, outp);
    node_k<<<dim3((NV_ + 255) / 256), blk, 0, stream>>>(hbel, vbel, lphi2, outp);
}

// Round 7
// 208.754 us; speedup vs baseline: 2.0886x; 1.0672x over previous
//
#include <hip/hip_runtime.h>
#include <hip/hip_bf16.h>
#include <math.h>

#define D_    256
#define NSQ   4096
#define NL    2
#define HID_  1024
#define R0_   3969
#define EH_   3906
#define EV_   3906
#define NV_   3844
#define LN_EPS_ 1e-5f
#define CLAMP_  1e-8f
#define TK_    64

typedef float f32x4 __attribute__((ext_vector_type(4)));
typedef __bf16 bf16x8 __attribute__((ext_vector_type(8)));
typedef unsigned short u16x8 __attribute__((ext_vector_type(8)));

__device__ __forceinline__ void gload_lds16(const void* g, void* l) {
    __builtin_amdgcn_global_load_lds(
        (const __attribute__((address_space(1))) void*)g,
        (__attribute__((address_space(3))) void*)l, 16, 0, 0);
}

// =================== templated bf16 MFMA GEMM body, double-buffered ===================
template<int BM, int BN>
__device__ __forceinline__ void gemm_body(
    const __hip_bfloat16* __restrict__ A, const __hip_bfloat16* __restrict__ Bt,
    const float* __restrict__ bias,
    const float* __restrict__ resf, const __hip_bfloat16* __restrict__ resb,
    void* __restrict__ C, int M, int N, int K, int relu, int outmode,
    int bx, int by)
{
    constexpr int WR  = BM / 64;
    constexpr int WC  = 4 / WR;
    constexpr int WNT = BN / WC;
    constexpr int NF  = WNT / 16;
    constexpr int ACH = BM / 64;
    constexpr int BCH = BN / 64;
    constexpr int ASZ = BM * 32;

    __shared__ __hip_bfloat16 sm[2][(BM + BN) * 32];

    const int t = threadIdx.x;
    const int lane = t & 63, wave = t >> 6;
    const int ln = lane & 15, lg = lane >> 4;
    const int wr = (WR == 1) ? 0 : (wave >> 1);
    const int wc = (WR == 1) ? wave : (wave & 1);
    const int row0 = bx * BM, col0 = by * BN;

    int aoff[ACH], boff[BCH];
    #pragma unroll
    for (int c = 0; c < ACH; ++c) {
        int e = (c * 256 + t) * 8;
        int row = e >> 5, slot = (e >> 3) & 3;
        int kg = slot ^ (row & 3) ^ ((row >> 2) & 3);
        aoff[c] = row * K + kg * 8;
    }
    #pragma unroll
    for (int c = 0; c < BCH; ++c) {
        int e = (c * 256 + t) * 8;
        int row = e >> 5, slot = (e >> 3) & 3;
        int kg = slot ^ (row & 3) ^ ((row >> 2) & 3);
        boff[c] = row * K + kg * 8;
    }
    const int sw = (ln & 3) ^ ((ln >> 2) & 3);

    const __hip_bfloat16* Ab = A + (size_t)row0 * K;
    const __hip_bfloat16* Bb = Bt + (size_t)col0 * K;

    f32x4 acc[4][NF];
    #pragma unroll
    for (int m = 0; m < 4; ++m)
        #pragma unroll
        for (int n = 0; n < NF; ++n) acc[m][n] = f32x4{0.f, 0.f, 0.f, 0.f};

    auto STAGE = [&](int k0, int buf) {
        #pragma unroll
        for (int c = 0; c < ACH; ++c)
            gload_lds16(Ab + k0 + aoff[c], (char*)&sm[buf][0] + (c * 256 + t) * 16);
        #pragma unroll
        for (int c = 0; c < BCH; ++c)
            gload_lds16(Bb + k0 + boff[c], (char*)&sm[buf][ASZ] + (c * 256 + t) * 16);
    };

    STAGE(0, 0);
    __syncthreads();
    int cur = 0;
    for (int k0 = 0; k0 < K; k0 += 32) {
        if (k0 + 32 < K) STAGE(k0 + 32, cur ^ 1);
        bf16x8 af[4], bfr[NF];
        #pragma unroll
        for (int m = 0; m < 4; ++m)
            af[m] = *(const bf16x8*)((const char*)&sm[cur][0] +
                     (size_t)(wr * 64 + m * 16 + ln) * 64 + ((lg ^ sw) << 4));
        #pragma unroll
        for (int n = 0; n < NF; ++n)
            bfr[n] = *(const bf16x8*)((const char*)&sm[cur][ASZ] +
                     (size_t)(wc * WNT + n * 16 + ln) * 64 + ((lg ^ sw) << 4));
        #pragma unroll
        for (int m = 0; m < 4; ++m)
            #pragma unroll
            for (int n = 0; n < NF; ++n)
                acc[m][n] = __builtin_amdgcn_mfma_f32_16x16x32_bf16(
                    af[m], bfr[n], acc[m][n], 0, 0, 0);
        __syncthreads();
        cur ^= 1;
    }

    #pragma unroll
    for (int m = 0; m < 4; ++m) {
        const int rowb = row0 + wr * 64 + m * 16 + lg * 4;
        #pragma unroll
        for (int n = 0; n < NF; ++n) {
            const int col = col0 + wc * WNT + n * 16 + ln;
            const float bv = bias ? bias[col] : 0.f;
            if (outmode == 2) {
                union { ushort4 u4; __hip_bfloat16 h[4]; } pk;
                #pragma unroll
                for (int r = 0; r < 4; ++r) {
                    float v = acc[m][n][r] + bv;
                    if (relu) v = fmaxf(v, 0.f);
                    pk.h[r] = __float2bfloat16(v);
                }
                *(ushort4*)((__hip_bfloat16*)C + (size_t)col * M + rowb) = pk.u4;
            } else if (outmode == 3) {
                union { ushort4 u4; __hip_bfloat16 h[4]; } pk;
                #pragma unroll
                for (int r = 0; r < 4; ++r) {
                    float v = acc[m][n][r] + bv;
                    if (relu) v = fmaxf(v, 0.f);
                    pk.h[r] = __float2bfloat16(v);
                }
                size_t off = ((size_t)((rowb >> 5) * 16 + (col >> 4)) << 9)
                           + (size_t)(((rowb >> 3) & 3) * 16 + (col & 15)) * 8
                           + (rowb & 7);
                *(ushort4*)((__hip_bfloat16*)C + off) = pk.u4;
            } else {
                #pragma unroll
                for (int r = 0; r < 4; ++r) {
                    float v = acc[m][n][r] + bv;
                    if (relu) v = fmaxf(v, 0.f);
                    const size_t idx = (size_t)(rowb + r) * N + col;
                    if (resf) v += resf[idx];
                    if (resb) v += __bfloat162float(resb[idx]);
                    if (outmode == 0) ((float*)C)[idx] = v;
                    else ((__hip_bfloat16*)C)[idx] = __float2bfloat16(v);
                }
            }
        }
    }
}

// ============ fused QK + V projection: grid (64, 6); y<4 -> QK, y>=4 -> V ============
__global__ __launch_bounds__(256) void gemm_qkv(
    const __hip_bfloat16* __restrict__ xb,
    const __hip_bfloat16* __restrict__ wqkt2, const __hip_bfloat16* __restrict__ wvt2,
    const float* __restrict__ bqk2, const float* __restrict__ bv,
    __hip_bfloat16* __restrict__ qkb, __hip_bfloat16* __restrict__ vf, int l)
{
    const __hip_bfloat16* Bt;
    const float* bias;
    void* C;
    int N, outmode, by;
    if (blockIdx.y < 4) {
        Bt = wqkt2 + (size_t)l * 131072; bias = bqk2 + l * 512;
        C = qkb; N = 512; outmode = 1; by = blockIdx.y;
    } else {
        Bt = wvt2 + (size_t)l * 65536; bias = bv + l * D_;
        C = vf; N = D_; outmode = 3; by = blockIdx.y - 4;
    }
    gemm_body<64, 128>(xb, Bt, bias, nullptr, nullptr, C, NSQ, N, D_, 0, outmode,
                       blockIdx.x, by);
}

// ===== fused proj GEMM + LayerNorm: 16 complete rows per block, grid 256 =====
// y[16][256] = ctx[16][256] @ wdt^T + bd; stash in LDS; in-block LN(y + res).
// fin=0: write x (f32) + xb (bf16); fin=1: scatter feats via reverse r0 map.
__global__ __launch_bounds__(256) void projln_k(
    const __hip_bfloat16* __restrict__ ctxb, const __hip_bfloat16* __restrict__ wdt,
    const float* __restrict__ bd, const float* __restrict__ resf,
    const float* __restrict__ g, const float* __restrict__ b,
    float* __restrict__ xo, __hip_bfloat16* __restrict__ xob,
    __hip_bfloat16* __restrict__ feats, int fin)
{
    __shared__ __hip_bfloat16 smA[2][16 * 64];     // 2 x 2KB
    __shared__ __hip_bfloat16 smB[2][256 * 64];    // 2 x 32KB
    __shared__ float yl[16][260];                  // 16.6KB, pad->2-way aliasing only

    const int t = threadIdx.x;
    const int lane = t & 63, wave = t >> 6;
    const int ln = lane & 15, lg = lane >> 4;
    const int row0 = blockIdx.x * 16;

    int boff[8];
    #pragma unroll
    for (int c = 0; c < 8; ++c) {
        int e = c * 256 + t;
        int row = e >> 3, slot = e & 7;
        boff[c] = row * D_ + (slot ^ (row & 7)) * 8;
    }
    int aoff;
    {
        int row = t >> 3, slot = t & 7;    // valid for t<128 (rows 0..15)
        aoff = row * D_ + (slot ^ (row & 7)) * 8;
    }
    const __hip_bfloat16* Ab = ctxb + (size_t)row0 * D_;

    f32x4 acc[4];
    #pragma unroll
    for (int n = 0; n < 4; ++n) acc[n] = f32x4{0.f, 0.f, 0.f, 0.f};

    auto STAGE = [&](int k0, int buf) {
        #pragma unroll
        for (int c = 0; c < 8; ++c)
            gload_lds16(wdt + k0 + boff[c], (char*)&smB[buf][0] + (c * 256 + t) * 16);
        if (t < 128)   // waves 0,1 (uniform per wave)
            gload_lds16(Ab + k0 + aoff, (char*)&smA[buf][0] + t * 16);
    };

    STAGE(0, 0);
    __syncthreads();
    int cur = 0;
    for (int k0 = 0; k0 < D_; k0 += 64) {
        if (k0 + 64 < D_) STAGE(k0 + 64, cur ^ 1);
        #pragma unroll
        for (int kh = 0; kh < 2; ++kh) {
            bf16x8 af = *(const bf16x8*)((const char*)&smA[cur][0] +
                         ln * 128 + (((kh * 4 + lg) ^ (ln & 7)) << 4));
            #pragma unroll
            for (int n = 0; n < 4; ++n) {
                const int row = wave * 64 + n * 16 + ln;
                bf16x8 bf_ = *(const bf16x8*)((const char*)&smB[cur][0] +
                              row * 128 + (((kh * 4 + lg) ^ (row & 7)) << 4));
                acc[n] = __builtin_amdgcn_mfma_f32_16x16x32_bf16(af, bf_, acc[n], 0, 0, 0);
            }
        }
        __syncthreads();
        cur ^= 1;
    }

    // stash y (GEMM + bias) to LDS
    #pragma unroll
    for (int n = 0; n < 4; ++n) {
        const int col = wave * 64 + n * 16 + ln;
        const float bv = bd[col];
        #pragma unroll
        for (int r = 0; r < 4; ++r)
            yl[lg * 4 + r][col] = acc[n][r] + bv;
    }
    __syncthreads();

    // LN: wave handles rows wave*4 .. wave*4+3 (residual added here, coalesced)
    for (int i = 0; i < 4; ++i) {
        const int lrow = wave * 4 + i;
        const int row = row0 + lrow;
        float4 yv = *(const float4*)&yl[lrow][lane * 4];
        float4 rv = *(const float4*)(resf + (size_t)row * D_ + lane * 4);
        float vx = yv.x + rv.x, vy = yv.y + rv.y, vz = yv.z + rv.z, vw = yv.w + rv.w;
        float s = vx + vy + vz + vw;
        #pragma unroll
        for (int off = 1; off < 64; off <<= 1) s += __shfl_xor(s, off);
        float mu = s * (1.f / D_);
        float dx = vx - mu, dy = vy - mu, dz = vz - mu, dw = vw - mu;
        float q = dx * dx + dy * dy + dz * dz + dw * dw;
        #pragma unroll
        for (int off = 1; off < 64; off <<= 1) q += __shfl_xor(q, off);
        float inv = rsqrtf(q * (1.f / D_) + LN_EPS_);
        float4 gg = *(const float4*)(g + lane * 4);
        float4 bb = *(const float4*)(b + lane * 4);
        float4 o;
        o.x = dx * inv * gg.x + bb.x;
        o.y = dy * inv * gg.y + bb.y;
        o.z = dz * inv * gg.z + bb.z;
        o.w = dw * inv * gg.w + bb.w;
        union { ushort4 u4; __hip_bfloat16 h[4]; } pk;
        pk.h[0] = __float2bfloat16(o.x); pk.h[1] = __float2bfloat16(o.y);
        pk.h[2] = __float2bfloat16(o.z); pk.h[3] = __float2bfloat16(o.w);
        if (!fin) {
            *(float4*)(xo + (size_t)row * D_ + lane * 4) = o;
            *(ushort4*)(xob + (size_t)row * D_ + lane * 4) = pk.u4;
        } else {
            const int r = row >> 6, c = row & 63;
            if (r < 63 && c < 63)
                *(ushort4*)(feats + (size_t)(r * 63 + c) * 1024 + lane * 4) = pk.u4;
            if (r < 63 && c > 0)
                *(ushort4*)(feats + (size_t)(r * 63 + c - 1) * 1024 + 256 + lane * 4) = pk.u4;
            if (r > 0 && c < 63)
                *(ushort4*)(feats + (size_t)((r - 1) * 63 + c) * 1024 + 512 + lane * 4) = pk.u4;
            if (r > 0 && c > 0)
                *(ushort4*)(feats + (size_t)((r - 1) * 63 + c - 1) * 1024 + 768 + lane * 4) = pk.u4;
        }
    }
}

// ======= pipelined 128x128 MLP GEMM, BK=64: 256 thr / 4 waves (64x64 per wave) =======
__global__ __launch_bounds__(256, 2) void gemm_128p(
    const __hip_bfloat16* __restrict__ A, const __hip_bfloat16* __restrict__ Bt,
    const float* __restrict__ bias, const __hip_bfloat16* __restrict__ resb,
    __hip_bfloat16* __restrict__ C, int M, int N, int K, int relu)
{
    __shared__ __hip_bfloat16 sm[3][16384];   // 3 bufs x (A 128x64 | B 128x64) = 96KB

    const int t = threadIdx.x;
    const int lane = t & 63, wave = t >> 6;
    const int ln = lane & 15, lg = lane >> 4;
    const int wr = wave >> 1, wc = wave & 1;
    const int row0 = blockIdx.x * 128, col0 = blockIdx.y * 128;

    int aoff[4];
    #pragma unroll
    for (int c = 0; c < 4; ++c) {
        int e = c * 256 + t;
        int row = e >> 3, slot = e & 7;
        int kg = slot ^ (row & 7);
        aoff[c] = row * K + kg * 8;
    }

    const __hip_bfloat16* Ab = A + (size_t)row0 * K;
    const __hip_bfloat16* Bb = Bt + (size_t)col0 * K;

    f32x4 acc[4][4];
    #pragma unroll
    for (int m = 0; m < 4; ++m)
        #pragma unroll
        for (int n = 0; n < 4; ++n) acc[m][n] = f32x4{0.f, 0.f, 0.f, 0.f};

    auto STAGE = [&](int tile, int buf) {
        const int k0 = tile * 64;
        #pragma unroll
        for (int c = 0; c < 4; ++c) {
            gload_lds16(Ab + k0 + aoff[c], (char*)&sm[buf][0] + (c * 256 + t) * 16);
            gload_lds16(Bb + k0 + aoff[c], (char*)&sm[buf][8192] + (c * 256 + t) * 16);
        }
    };

    const int NT = K >> 6;
    STAGE(0, 0); STAGE(1, 1);

    int buf = 0;
    for (int tt = 0; tt < NT; ++tt) {
        const int rem = NT - 1 - tt;
        if (rem >= 1) asm volatile("s_waitcnt vmcnt(8)" ::: "memory");
        else          asm volatile("s_waitcnt vmcnt(0)" ::: "memory");
        __builtin_amdgcn_sched_barrier(0);
        __builtin_amdgcn_s_barrier();
        if (tt + 2 < NT) STAGE(tt + 2, (buf + 2 >= 3) ? buf - 1 : buf + 2);

        const char* base = (const char*)&sm[buf][0];
        #pragma unroll
        for (int kh = 0; kh < 2; ++kh) {
            bf16x8 af[4], bfr[4];
            #pragma unroll
            for (int m = 0; m < 4; ++m) {
                const int row = wr * 64 + m * 16 + ln;
                af[m] = *(const bf16x8*)(base + row * 128 +
                         (((kh * 4 + lg) ^ (row & 7)) << 4));
            }
            #pragma unroll
            for (int n = 0; n < 4; ++n) {
                const int row = wc * 64 + n * 16 + ln;
                bfr[n] = *(const bf16x8*)(base + 16384 + row * 128 +
                          (((kh * 4 + lg) ^ (row & 7)) << 4));
            }
            #pragma unroll
            for (int m = 0; m < 4; ++m)
                #pragma unroll
                for (int n = 0; n < 4; ++n)
                    acc[m][n] = __builtin_amdgcn_mfma_f32_16x16x32_bf16(
                        af[m], bfr[n], acc[m][n], 0, 0, 0);
        }
        buf = (buf + 1 >= 3) ? 0 : buf + 1;
    }

    #pragma unroll
    for (int m = 0; m < 4; ++m) {
        const int rowb = row0 + wr * 64 + m * 16 + lg * 4;
        #pragma unroll
        for (int n = 0; n < 4; ++n) {
            const int col = col0 + wc * 64 + n * 16 + ln;
            const float bv = bias[col];
            #pragma unroll
            for (int r = 0; r < 4; ++r) {
                float v = acc[m][n][r] + bv;
                if (relu) v = fmaxf(v, 0.f);
                const size_t idx = (size_t)(rowb + r) * N + col;
                if (resb) v += __bfloat162float(resb[idx]);
                C[idx] = __float2bfloat16(v);
            }
        }
    }
}

// ========= small-N GEMM fused with softmax+belief+R0 energy (N=16) =========
__global__ __launch_bounds__(256) void gemm_n16b(
    const __hip_bfloat16* __restrict__ A, const __hip_bfloat16* __restrict__ Bt,
    const float* __restrict__ bias, const float* __restrict__ lphi0,
    float* __restrict__ beliefs, float* __restrict__ out, int M, int K)
{
    const int t = threadIdx.x, lane = t & 63, wave = t >> 6;
    const int ln = lane & 15, lg = lane >> 4;
    const int r0 = blockIdx.x * 64 + wave * 16;
    f32x4 acc = {0.f, 0.f, 0.f, 0.f};
    for (int k0 = 0; k0 < K; k0 += 32) {
        bf16x8 a = *(const bf16x8*)(A + (size_t)(r0 + ln) * K + k0 + lg * 8);
        bf16x8 b = *(const bf16x8*)(Bt + (size_t)ln * K + k0 + lg * 8);
        acc = __builtin_amdgcn_mfma_f32_16x16x32_bf16(a, b, acc, 0, 0, 0);
    }
    float e = 0.f;
    #pragma unroll
    for (int r = 0; r < 4; ++r) {
        const int row = r0 + lg * 4 + r;
        float v = acc[r] + bias[ln];
        float mx = v;
        mx = fmaxf(mx, __shfl_xor(mx, 1));
        mx = fmaxf(mx, __shfl_xor(mx, 2));
        mx = fmaxf(mx, __shfl_xor(mx, 4));
        mx = fmaxf(mx, __shfl_xor(mx, 8));
        float ex = __expf(v - mx);
        float s = ex;
        s += __shfl_xor(s, 1);
        s += __shfl_xor(s, 2);
        s += __shfl_xor(s, 4);
        s += __shfl_xor(s, 8);
        if (row < R0_) {
            float bb = ex / s;
            beliefs[(size_t)row * 16 + ln] = bb;
            float bc = fmaxf(bb, CLAMP_);
            e += bc * (logf(bc) - lphi0[(size_t)row * 16 + ln]);
        }
    }
    #pragma unroll
    for (int off = 32; off; off >>= 1) e += __shfl_down(e, off);
    if (lane == 0) atomicAdd(&out[0], e);
}

// ====== fused prep (5700 blocks): castb | owt | attn-wt8 | catbias2 | mlp-wt4 ======
__global__ __launch_bounds__(256) void prep_k(
    const float* __restrict__ node_emb, __hip_bfloat16* __restrict__ xb,
    const float* __restrict__ outw, __hip_bfloat16* __restrict__ outwt,
    const float* __restrict__ Wq, const float* __restrict__ Wk,
    const float* __restrict__ Wv, const float* __restrict__ Wd,
    __hip_bfloat16* __restrict__ wqkt2, __hip_bfloat16* __restrict__ wvt2,
    __hip_bfloat16* __restrict__ wdt2,
    const float* __restrict__ bq, const float* __restrict__ bk,
    float* __restrict__ bqk2,
    const float* __restrict__ M0, const float* __restrict__ M1,
    const float* __restrict__ M2, const float* __restrict__ M3,
    __hip_bfloat16* __restrict__ T0, __hip_bfloat16* __restrict__ T1,
    __hip_bfloat16* __restrict__ T2, __hip_bfloat16* __restrict__ T3,
    float* __restrict__ outp)
{
    __shared__ float tile[32][33];
    const int b = blockIdx.x, t = threadIdx.x;
    if (b == 0 && t < 2) outp[t] = 0.f;
    if (b < 1024) {
        int p = b * 256 + t;
        float4 v = *(const float4*)(node_emb + (size_t)p * 4);
        union { ushort4 u4; __hip_bfloat16 h[4]; } pk;
        pk.h[0] = __float2bfloat16(v.x); pk.h[1] = __float2bfloat16(v.y);
        pk.h[2] = __float2bfloat16(v.z); pk.h[3] = __float2bfloat16(v.w);
        *(ushort4*)(xb + (size_t)p * 4) = pk.u4;
    } else if (b < 1088) {
        int i = (b - 1024) * 256 + t;
        int n = i >> 10, k = i & 1023;
        outwt[i] = __float2bfloat16(outw[k * 16 + n]);
    } else if (b < 1600) {
        int idx = b - 1088;
        int z = idx >> 6, bx = (idx >> 3) & 7, by = idx & 7;
        int l = z >> 2, w = z & 3;
        const float* W = (w == 0 ? Wq : w == 1 ? Wk : w == 2 ? Wv : Wd) + (size_t)l * 65536;
        __hip_bfloat16* Wt = w == 0 ? wqkt2 + (size_t)l * 131072
                           : w == 1 ? wqkt2 + (size_t)l * 131072 + 65536
                           : w == 2 ? wvt2 + (size_t)l * 65536
                                    : wdt2 + (size_t)l * 65536;
        int k0 = bx * 32, n0 = by * 32;
        int r = t >> 3, c4 = (t & 7) * 4;
        float4 v = *(const float4*)(W + (size_t)(k0 + r) * 256 + n0 + c4);
        tile[r][c4 + 0] = v.x; tile[r][c4 + 1] = v.y;
        tile[r][c4 + 2] = v.z; tile[r][c4 + 3] = v.w;
        __syncthreads();
        union { ushort4 u4; __hip_bfloat16 h[4]; } pk;
        #pragma unroll
        for (int i = 0; i < 4; ++i) pk.h[i] = __float2bfloat16(tile[c4 + i][r]);
        *(ushort4*)(Wt + (size_t)(n0 + r) * 256 + k0 + c4) = pk.u4;
    } else if (b < 1604) {
        int idx = (b - 1600) * 256 + t;
        int l = idx >> 9, j = idx & 511;
        bqk2[idx] = j < 256 ? bq[l * 256 + j] : bk[l * 256 + j - 256];
    } else {
        int idx = b - 1604;
        int z = idx >> 10, rem = idx & 1023;
        const float* W = z == 0 ? M0 : z == 1 ? M1 : z == 2 ? M2 : M3;
        __hip_bfloat16* Wt = z == 0 ? T0 : z == 1 ? T1 : z == 2 ? T2 : T3;
        int k0 = (rem >> 5) * 32, n0 = (rem & 31) * 32;
        int r = t >> 3, c4 = (t & 7) * 4;
        float4 v = *(const float4*)(W + (size_t)(k0 + r) * 1024 + n0 + c4);
        tile[r][c4 + 0] = v.x; tile[r][c4 + 1] = v.y;
        tile[r][c4 + 2] = v.z; tile[r][c4 + 3] = v.w;
        __syncthreads();
        union { ushort4 u4; __hip_bfloat16 h[4]; } pk;
        #pragma unroll
        for (int i = 0; i < 4; ++i) pk.h[i] = __float2bfloat16(tile[c4 + i][r]);
        *(ushort4*)(Wt + (size_t)(n0 + r) * 1024 + k0 + c4) = pk.u4;
    }
}

// ============ flash attention: 8 waves, TK=64, counted vmcnt =============
template<int KS>
__global__ __launch_bounds__(512, 2) void attn_mfma_t(
    const __hip_bfloat16* __restrict__ qk, const __hip_bfloat16* __restrict__ vf,
    __hip_bfloat16* __restrict__ po, float* __restrict__ pm, float* __restrict__ pl)
{
    constexpr int KRANGE = NSQ / KS;
    constexpr int NT = KRANGE / TK_;
    constexpr int VOFF = 65536;
    constexpr int POFF = 98304;
    const int t = threadIdx.x;
    const int wave = t >> 6, lane = t & 63;
    const int ln = lane & 15, lg = lane >> 4;
    const int q0 = blockIdx.x * 128 + wave * 16;
    const int ks = blockIdx.y;
    const int k0 = ks * KRANGE;

    __shared__ __align__(16) char smem[116736];

    bf16x8 qa[8];
    #pragma unroll
    for (int s = 0; s < 8; ++s)
        qa[s] = *(const bf16x8*)(qk + (size_t)(q0 + ln) * 512 + s * 32 + lg * 8);

    int srcoff[4];
    #pragma unroll
    for (int c = 0; c < 4; ++c) {
        int row = c * 16 + (t >> 5);
        int g = (t & 31) ^ ((row & 15) << 1);
        srcoff[c] = row * 512 + 256 + g * 8;
    }
    int rb[8];
    #pragma unroll
    for (int s8 = 0; s8 < 8; ++s8)
        rb[s8] = ln * 512 + (((s8 * 4 + lg) ^ (ln << 1)) << 4);

    f32x4 o[16];
    #pragma unroll
    for (int nt = 0; nt < 16; ++nt) o[nt] = f32x4{0.f, 0.f, 0.f, 0.f};
    float rm = -1e30f, rl = 0.f;

    {
        const __hip_bfloat16* src = qk + (size_t)k0 * 512;
        #pragma unroll
        for (int c = 0; c < 4; ++c)
            gload_lds16(src + srcoff[c], smem + c * 8192 + t * 16);
    }
    __syncthreads();

    for (int it = 0; it < NT; ++it) {
        const int cur = it & 1;
        {
            const __hip_bfloat16* vsrc = vf + ((size_t)((k0 + it * TK_) >> 5) << 13);
            #pragma unroll
            for (int c = 0; c < 4; ++c) {
                int idx = c * 512 + t;
                gload_lds16(vsrc + (size_t)idx * 8, smem + VOFF + idx * 16);
            }
        }
        {
            const int itn = (it + 1 < NT) ? it + 1 : it;
            const __hip_bfloat16* src = qk + (size_t)(k0 + itn * TK_) * 512;
            #pragma unroll
            for (int c = 0; c < 4; ++c)
                gload_lds16(src + srcoff[c], smem + (cur ^ 1) * 32768 + c * 8192 + t * 16);
        }
        const char* kbase = smem + cur * 32768;
        f32x4 s4[4];
        #pragma unroll
        for (int nt = 0; nt < 4; ++nt) {
            f32x4 acc = {0.f, 0.f, 0.f, 0.f};
            #pragma unroll
            for (int s8 = 0; s8 < 8; ++s8) {
                bf16x8 kb = *(const bf16x8*)(kbase + nt * 8192 + rb[s8]);
                acc = __builtin_amdgcn_mfma_f32_16x16x32_bf16(kb, qa[s8], acc, 0, 0, 0);
            }
            s4[nt] = acc;
        }
        float mx = -1e30f;
        #pragma unroll
        for (int nt = 0; nt < 4; ++nt)
            #pragma unroll
            for (int r = 0; r < 4; ++r) mx = fmaxf(mx, s4[nt][r]);
        mx = fmaxf(mx, __shfl_xor(mx, 16));
        mx = fmaxf(mx, __shfl_xor(mx, 32));
        float sc = 1.f;
        if (__any(mx > rm + 8.f)) {
            float mnew = fmaxf(rm, mx);
            sc = __expf(rm - mnew);
            rm = mnew;
            float scr[4];
            #pragma unroll
            for (int r = 0; r < 4; ++r) scr[r] = __shfl(sc, lg * 4 + r);
            #pragma unroll
            for (int nt = 0; nt < 16; ++nt)
                #pragma unroll
                for (int r = 0; r < 4; ++r) o[nt][r] *= scr[r];
        }
        float rs = 0.f;
        #pragma unroll
        for (int nt = 0; nt < 4; ++nt)
            #pragma unroll
            for (int r = 0; r < 4; ++r) {
                float p = __expf(s4[nt][r] - rm);
                s4[nt][r] = p;
                rs += p;
            }
        rs += __shfl_xor(rs, 16);
        rs += __shfl_xor(rs, 32);
        rl = rl * sc + rs;
        char* prow = smem + POFF + wave * 2304 + ln * 144;
        #pragma unroll
        for (int nt = 0; nt < 4; ++nt) {
            union { ushort4 u4; __hip_bfloat16 h[4]; } pk;
            #pragma unroll
            for (int r = 0; r < 4; ++r) pk.h[r] = __float2bfloat16(s4[nt][r]);
            *(ushort4*)(prow + nt * 32 + lg * 8) = pk.u4;
        }
        asm volatile("s_waitcnt lgkmcnt(0)" ::: "memory");
        __builtin_amdgcn_sched_barrier(0);
        bf16x8 pa0 = *(const bf16x8*)(prow + lg * 16);
        bf16x8 pa1 = *(const bf16x8*)(prow + 64 + lg * 16);
        asm volatile("s_waitcnt vmcnt(4)" ::: "memory");
        __builtin_amdgcn_sched_barrier(0);
        __builtin_amdgcn_s_barrier();
        const char* vl = smem + VOFF;
        #pragma unroll
        for (int ntd = 0; ntd < 16; ++ntd) {
            bf16x8 vb0 = *(const bf16x8*)(vl + ntd * 1024 + lane * 16);
            bf16x8 vb1 = *(const bf16x8*)(vl + 16384 + ntd * 1024 + lane * 16);
            o[ntd] = __builtin_amdgcn_mfma_f32_16x16x32_bf16(pa0, vb0, o[ntd], 0, 0, 0);
            o[ntd] = __builtin_amdgcn_mfma_f32_16x16x32_bf16(pa1, vb1, o[ntd], 0, 0, 0);
        }
        __syncthreads();
    }
    unsigned short* ob = (unsigned short*)(smem + wave * 8448);
    #pragma unroll
    for (int nt = 0; nt < 16; ++nt)
        #pragma unroll
        for (int r = 0; r < 4; ++r) {
            __hip_bfloat16 h = __float2bfloat16(o[nt][r]);
            ob[(lg * 4 + r) * 264 + nt * 16 + ln] = *(unsigned short*)&h;
        }
    asm volatile("s_waitcnt lgkmcnt(0)" ::: "memory");
    __builtin_amdgcn_sched_barrier(0);
    unsigned short* pob = (unsigned short*)po;
    #pragma unroll
    for (int i = 0; i < 8; ++i) {
        int f = i * 64 + lane;
        int row = f >> 5, dc = f & 31;
        u16x8 vv = *(const u16x8*)(ob + row * 264 + dc * 8);
        *(u16x8*)(pob + ((size_t)ks * NSQ + q0 + row) * D_ + dc * 8) = vv;
    }
    if (lane < 16) {
        pm[ks * NSQ + q0 + lane] = rm;
        pl[ks * NSQ + q0 + lane] = rl;
    }
}

// ============ combine: vectorized u16x8, 8 elems/thread, grid 512 ============
template<int KS>
__global__ __launch_bounds__(256) void attn_combine_t(
    const __hip_bfloat16* __restrict__ po, const float* __restrict__ pm,
    const float* __restrict__ pl, __hip_bfloat16* __restrict__ ctx)
{
    const int idx8 = blockIdx.x * 256 + threadIdx.x;
    const int row = idx8 >> 5;
    float m[KS], ms = -1e30f;
    #pragma unroll
    for (int s = 0; s < KS; ++s) { m[s] = pm[s * NSQ + row]; ms = fmaxf(ms, m[s]); }
    float l = 0.f, w[KS];
    #pragma unroll
    for (int s = 0; s < KS; ++s) {
        w[s] = __expf(m[s] - ms);
        l += w[s] * pl[s * NSQ + row];
    }
    const float inv = 1.f / l;
    float num[8];
    #pragma unroll
    for (int j = 0; j < 8; ++j) num[j] = 0.f;
    #pragma unroll
    for (int s = 0; s < KS; ++s) {
        u16x8 v = *(const u16x8*)(po + (size_t)s * (NSQ * D_) + (size_t)idx8 * 8);
        #pragma unroll
        for (int j = 0; j < 8; ++j) {
            union { float f; unsigned u; } cv;
            cv.u = (unsigned)v[j] << 16;
            num[j] += w[s] * cv.f;
        }
    }
    union { u16x8 u8; __hip_bfloat16 h[8]; } pk;
    #pragma unroll
    for (int j = 0; j < 8; ++j) pk.h[j] = __float2bfloat16(num[j] * inv);
    *(u16x8*)(ctx + (size_t)idx8 * 8) = pk.u8;
}

// === fused edges + nodes: grid (16,3); y=0 h-edges, y=1 v-edges, y=2 nodes ===
// nodes recompute the 4 incident edge beliefs from the 4 surrounding plaquettes
// (identical formulas/op-order as the edge paths) -> no hbel/vbel round-trip.
__global__ __launch_bounds__(256) void edge_node_k(
    const float* __restrict__ beliefs, const float* __restrict__ lphih,
    const float* __restrict__ lphiv, const float* __restrict__ lphi2,
    float* __restrict__ out)
{
    const int e = blockIdx.x * 256 + threadIdx.x;
    float el = 0.f, ml = 0.f;
    if (blockIdx.y == 0) {
        if (e < EH_) {
            const float* bA = beliefs + (size_t)e * 16;
            const float* bB = beliefs + (size_t)(e + 63) * 16;
            float s0[4] = {0,0,0,0}, s1[4] = {0,0,0,0};
            #pragma unroll
            for (int ab = 0; ab < 4; ++ab)
                #pragma unroll
                for (int cd = 0; cd < 4; ++cd) {
                    s0[cd] += bA[ab * 4 + cd];
                    s1[ab] += bB[ab * 4 + cd];
                }
            #pragma unroll
            for (int z = 0; z < 4; ++z) {
                float hb = 0.5f * (s0[z] + s1[z]);
                float d0 = s0[z] - hb, d1 = s1[z] - hb;
                ml += d0 * d0 + d1 * d1;
                float bc = fmaxf(hb, CLAMP_);
                el -= bc * (logf(bc) - lphih[e * 4 + z]);
            }
        }
    } else if (blockIdx.y == 1) {
        if (e < EV_) {
            int r = e / 62, c = e % 62 + 1;
            const float* bL = beliefs + (size_t)(r * 63 + c - 1) * 16;
            const float* bR = beliefs + (size_t)(r * 63 + c) * 16;
            float s0[4] = {0,0,0,0}, s1[4] = {0,0,0,0};
            #pragma unroll
            for (int a = 0; a < 2; ++a)
                #pragma unroll
                for (int bq = 0; bq < 2; ++bq)
                    #pragma unroll
                    for (int c2 = 0; c2 < 2; ++c2)
                        #pragma unroll
                        for (int d = 0; d < 2; ++d) {
                            int idx = a * 8 + bq * 4 + c2 * 2 + d;
                            s0[bq * 2 + d]  += bL[idx];
                            s1[a * 2 + c2] += bR[idx];
                        }
            #pragma unroll
            for (int z = 0; z < 4; ++z) {
                float vb = 0.5f * (s0[z] + s1[z]);
                float d0 = s0[z] - vb, d1 = s1[z] - vb;
                ml += d0 * d0 + d1 * d1;
                float bc = fmaxf(vb, CLAMP_);
                el -= bc * (logf(bc) - lphiv[e * 4 + z]);
            }
        }
    } else {
        if (e < NV_) {
            const int hl = (e / 62) * 63 + (e % 62);
            const float* P00 = beliefs + (size_t)hl * 16;
            const float* P01 = beliefs + (size_t)(hl + 1) * 16;
            const float* P10 = beliefs + (size_t)(hl + 63) * 16;
            const float* P11 = beliefs + (size_t)(hl + 64) * 16;
            // h-edge beliefs (hl: P00|P10, hr: P01|P11)
            float hbl[4], hbr[4];
            #pragma unroll
            for (int z = 0; z < 4; ++z) {
                float s0 = P00[z] + P00[4 + z] + P00[8 + z] + P00[12 + z];
                float s1 = P10[4 * z] + P10[4 * z + 1] + P10[4 * z + 2] + P10[4 * z + 3];
                hbl[z] = 0.5f * (s0 + s1);
                float t0 = P01[z] + P01[4 + z] + P01[8 + z] + P01[12 + z];
                float t1 = P11[4 * z] + P11[4 * z + 1] + P11[4 * z + 2] + P11[4 * z + 3];
                hbr[z] = 0.5f * (t0 + t1);
            }
            // v-edge beliefs (vu: P00|P01, vd: P10|P11)
            float vbu[4], vbd[4];
            #pragma unroll
            for (int z = 0; z < 4; ++z) {
                const int bqd = (z >> 1) * 4 + (z & 1);   // bq*4 + d
                const int ac2 = (z >> 1) * 8 + (z & 1) * 2; // a*8 + c2*2
                float s0 = P00[bqd] + P00[bqd + 2] + P00[8 + bqd] + P00[8 + bqd + 2];
                float s1 = P01[ac2] + P01[ac2 + 1] + P01[ac2 + 4] + P01[ac2 + 5];
                vbu[z] = 0.5f * (s0 + s1);
                float t0 = P10[bqd] + P10[bqd + 2] + P10[8 + bqd] + P10[8 + bqd + 2];
                float t1 = P11[ac2] + P11[ac2 + 1] + P11[ac2 + 4] + P11[ac2 + 5];
                vbd[z] = 0.5f * (t0 + t1);
            }
            #pragma unroll
            for (int z = 0; z < 2; ++z) {
                float n0 = hbl[z] + hbl[2 + z];
                float n1 = hbr[z * 2] + hbr[z * 2 + 1];
                float n2 = vbu[z] + vbu[2 + z];
                float n3 = vbd[z * 2] + vbd[z * 2 + 1];
                float nb = 0.25f * (n0 + n1 + n2 + n3);
                float d0 = n0 - nb, d1 = n1 - nb, d2 = n2 - nb, d3 = n3 - nb;
                ml += d0 * d0 + d1 * d1 + d2 * d2 + d3 * d3;
                float bc = fmaxf(nb, CLAMP_);
                el += bc * (logf(bc) - lphi2[e * 2 + z]);
            }
        }
    }
    #pragma unroll
    for (int off = 32; off; off >>= 1) { el += __shfl_down(el, off); ml += __shfl_down(ml, off); }
    if ((threadIdx.x & 63) == 0) { atomicAdd(&out[0], el); atomicAdd(&out[1], ml); }
}

// =======================================================================================
extern "C" void kernel_launch(void* const* d_in, const int* in_sizes, int n_in,
                              void* d_out, int out_size, void* d_ws, size_t ws_size,
                              hipStream_t stream)
{
    (void)in_sizes; (void)n_in; (void)out_size; (void)ws_size;
    const float* node_emb = (const float*)d_in[0];
    const float* Wq  = (const float*)d_in[1];
    const float* bq  = (const float*)d_in[2];
    const float* Wk  = (const float*)d_in[3];
    const float* bk  = (const float*)d_in[4];
    const float* Wv  = (const float*)d_in[5];
    const float* bv  = (const float*)d_in[6];
    const float* Wd  = (const float*)d_in[7];
    const float* bd  = (const float*)d_in[8];
    const float* lng = (const float*)d_in[9];
    const float* lnb = (const float*)d_in[10];
    const float* r1w1 = (const float*)d_in[11];
    const float* r1b1 = (const float*)d_in[12];
    const float* r1w2 = (const float*)d_in[13];
    const float* r1b2 = (const float*)d_in[14];
    const float* r2w1 = (const float*)d_in[15];
    const float* r2b1 = (const float*)d_in[16];
    const float* r2w2 = (const float*)d_in[17];
    const float* r2b2 = (const float*)d_in[18];
    const float* outw = (const float*)d_in[19];
    const float* outb = (const float*)d_in[20];
    const float* lphi0 = (const float*)d_in[21];
    const float* lphih = (const float*)d_in[22];
    const float* lphiv = (const float*)d_in[23];
    const float* lphi2 = (const float*)d_in[24];

    float* ws = (float*)d_ws;
    // persistent block (units: floats)
    float* x      = ws;                          // 1,048,576
    __hip_bfloat16* xb = (__hip_bfloat16*)(ws + 1048576);
    float* belief = ws + 1638400;
    __hip_bfloat16* outwt = (__hip_bfloat16*)(ws + 1736704);
    float* arena  = ws + 1744896;

    // phase A (attention) layout inside arena (float offsets)
    __hip_bfloat16* wqkt2 = (__hip_bfloat16*)(arena);                // [2][512][256]
    __hip_bfloat16* wvt2  = (__hip_bfloat16*)(arena + 131072);       // [2][256][256]
    __hip_bfloat16* wdt2  = (__hip_bfloat16*)(arena + 196608);       // [2][256][256]
    float* bqk2 = arena + 262144;                                    // [2][512]
    __hip_bfloat16* qkb = (__hip_bfloat16*)(arena + 263168);         // [4096][512]
    __hip_bfloat16* vf  = (__hip_bfloat16*)(arena + 1311744);        // packed V (2MB)
    __hip_bfloat16* ctxb = vf;                                       // alias: vf dead post-attn
    float* pm = arena + 2884608;                                     // [8][4096]
    float* pl = arena + 2950144;
    __hip_bfloat16* po = (__hip_bfloat16*)(arena + 3015680);         // 8M bf16 (KSPLIT=8)

    // phase B: feats + MLP weights OUTSIDE arena; hA/hB reuse dead attention arena.
    __hip_bfloat16* feats = (__hip_bfloat16*)(ws + 8954880);         // [4096][1024] bf16
    __hip_bfloat16* w1t = (__hip_bfloat16*)(ws + 11052032);
    __hip_bfloat16* w2t = (__hip_bfloat16*)(ws + 11576320);
    __hip_bfloat16* w3t = (__hip_bfloat16*)(ws + 12100608);
    __hip_bfloat16* w4t = (__hip_bfloat16*)(ws + 12624896);
    __hip_bfloat16* hA  = (__hip_bfloat16*)(arena);
    __hip_bfloat16* hB  = (__hip_bfloat16*)(arena + 2097152);

    float* outp = (float*)d_out;
    dim3 blk(256);
    dim3 blk512(512);
    prep_k<<<dim3(5700), blk, 0, stream>>>(node_emb, xb, outw, outwt,
                                           Wq, Wk, Wv, Wd, wqkt2, wvt2, wdt2,
                                           bq, bk, bqk2,
                                           r1w1, r1w2, r2w1, r2w2,
                                           w1t, w2t, w3t, w4t, outp);

    for (int l = 0; l < NL; ++l) {
        gemm_qkv<<<dim3(64, 6), blk, 0, stream>>>(xb, wqkt2, wvt2, bqk2, bv,
                                                  qkb, vf, l);
        attn_mfma_t<8><<<dim3(NSQ / 128, 8), blk512, 0, stream>>>(qkb, vf, po, pm, pl);
        attn_combine_t<8><<<dim3(NSQ * D_ / 2048), blk, 0, stream>>>(po, pm, pl, ctxb);
        projln_k<<<dim3(256), blk, 0, stream>>>(
            ctxb, wdt2 + (size_t)l * 65536, bd + l * D_,
            (l == 0 ? node_emb : x), lng + l * D_, lnb + l * D_,
            x, xb, feats, l);
    }

    dim3 gM(NSQ / 128, HID_ / 128);   // (32, 8) = 256 blocks, 1/CU
    gemm_128p<<<gM, blk, 0, stream>>>(feats, w1t, r1b1, nullptr,
                                      hA, NSQ, HID_, HID_, 1);
    gemm_128p<<<gM, blk, 0, stream>>>(hA, w2t, r1b2, feats,
                                      hB, NSQ, HID_, HID_, 1);
    gemm_128p<<<gM, blk, 0, stream>>>(hB, w3t, r2b1, nullptr,
                                      hA, NSQ, HID_, HID_, 1);
    gemm_128p<<<gM, blk, 0, stream>>>(hA, w4t, r2b2, hB,
                                      feats, NSQ, HID_, HID_, 1);

    gemm_n16b<<<dim3(NSQ / 64), blk, 0, stream>>>(feats, outwt, outb, lphi0,
                                                  belief, outp, NSQ, HID_);
    edge_node_k<<<dim3(16, 3), blk, 0, stream>>>(belief, lphih, lphiv, lphi2, outp);
}

// Round 8
// 201.532 us; speedup vs baseline: 2.1634x; 1.0358x over previous
//
#include <hip/hip_runtime.h>
#include <hip/hip_bf16.h>
#include <math.h>

#define D_    256
#define NSQ   4096
#define NL    2
#define HID_  1024
#define R0_   3969
#define EH_   3906
#define EV_   3906
#define NV_   3844
#define LN_EPS_ 1e-5f
#define CLAMP_  1e-8f
#define TK_    64

typedef float f32x4 __attribute__((ext_vector_type(4)));
typedef __bf16 bf16x8 __attribute__((ext_vector_type(8)));
typedef unsigned short u16x8 __attribute__((ext_vector_type(8)));

__device__ __forceinline__ void gload_lds16(const void* g, void* l) {
    __builtin_amdgcn_global_load_lds(
        (const __attribute__((address_space(1))) void*)g,
        (__attribute__((address_space(3))) void*)l, 16, 0, 0);
}

// =================== templated bf16 MFMA GEMM body, double-buffered ===================
template<int BM, int BN>
__device__ __forceinline__ void gemm_body(
    const __hip_bfloat16* __restrict__ A, const __hip_bfloat16* __restrict__ Bt,
    const float* __restrict__ bias,
    const float* __restrict__ resf, const __hip_bfloat16* __restrict__ resb,
    void* __restrict__ C, int M, int N, int K, int relu, int outmode,
    int bx, int by)
{
    constexpr int WR  = BM / 64;
    constexpr int WC  = 4 / WR;
    constexpr int WNT = BN / WC;
    constexpr int NF  = WNT / 16;
    constexpr int ACH = BM / 64;
    constexpr int BCH = BN / 64;
    constexpr int ASZ = BM * 32;

    __shared__ __hip_bfloat16 sm[2][(BM + BN) * 32];

    const int t = threadIdx.x;
    const int lane = t & 63, wave = t >> 6;
    const int ln = lane & 15, lg = lane >> 4;
    const int wr = (WR == 1) ? 0 : (wave >> 1);
    const int wc = (WR == 1) ? wave : (wave & 1);
    const int row0 = bx * BM, col0 = by * BN;

    int aoff[ACH], boff[BCH];
    #pragma unroll
    for (int c = 0; c < ACH; ++c) {
        int e = (c * 256 + t) * 8;
        int row = e >> 5, slot = (e >> 3) & 3;
        int kg = slot ^ (row & 3) ^ ((row >> 2) & 3);
        aoff[c] = row * K + kg * 8;
    }
    #pragma unroll
    for (int c = 0; c < BCH; ++c) {
        int e = (c * 256 + t) * 8;
        int row = e >> 5, slot = (e >> 3) & 3;
        int kg = slot ^ (row & 3) ^ ((row >> 2) & 3);
        boff[c] = row * K + kg * 8;
    }
    const int sw = (ln & 3) ^ ((ln >> 2) & 3);

    const __hip_bfloat16* Ab = A + (size_t)row0 * K;
    const __hip_bfloat16* Bb = Bt + (size_t)col0 * K;

    f32x4 acc[4][NF];
    #pragma unroll
    for (int m = 0; m < 4; ++m)
        #pragma unroll
        for (int n = 0; n < NF; ++n) acc[m][n] = f32x4{0.f, 0.f, 0.f, 0.f};

    auto STAGE = [&](int k0, int buf) {
        #pragma unroll
        for (int c = 0; c < ACH; ++c)
            gload_lds16(Ab + k0 + aoff[c], (char*)&sm[buf][0] + (c * 256 + t) * 16);
        #pragma unroll
        for (int c = 0; c < BCH; ++c)
            gload_lds16(Bb + k0 + boff[c], (char*)&sm[buf][ASZ] + (c * 256 + t) * 16);
    };

    STAGE(0, 0);
    __syncthreads();
    int cur = 0;
    for (int k0 = 0; k0 < K; k0 += 32) {
        if (k0 + 32 < K) STAGE(k0 + 32, cur ^ 1);
        bf16x8 af[4], bfr[NF];
        #pragma unroll
        for (int m = 0; m < 4; ++m)
            af[m] = *(const bf16x8*)((const char*)&sm[cur][0] +
                     (size_t)(wr * 64 + m * 16 + ln) * 64 + ((lg ^ sw) << 4));
        #pragma unroll
        for (int n = 0; n < NF; ++n)
            bfr[n] = *(const bf16x8*)((const char*)&sm[cur][ASZ] +
                     (size_t)(wc * WNT + n * 16 + ln) * 64 + ((lg ^ sw) << 4));
        #pragma unroll
        for (int m = 0; m < 4; ++m)
            #pragma unroll
            for (int n = 0; n < NF; ++n)
                acc[m][n] = __builtin_amdgcn_mfma_f32_16x16x32_bf16(
                    af[m], bfr[n], acc[m][n], 0, 0, 0);
        __syncthreads();
        cur ^= 1;
    }

    #pragma unroll
    for (int m = 0; m < 4; ++m) {
        const int rowb = row0 + wr * 64 + m * 16 + lg * 4;
        #pragma unroll
        for (int n = 0; n < NF; ++n) {
            const int col = col0 + wc * WNT + n * 16 + ln;
            const float bv = bias ? bias[col] : 0.f;
            if (outmode == 2) {
                union { ushort4 u4; __hip_bfloat16 h[4]; } pk;
                #pragma unroll
                for (int r = 0; r < 4; ++r) {
                    float v = acc[m][n][r] + bv;
                    if (relu) v = fmaxf(v, 0.f);
                    pk.h[r] = __float2bfloat16(v);
                }
                *(ushort4*)((__hip_bfloat16*)C + (size_t)col * M + rowb) = pk.u4;
            } else if (outmode == 3) {
                union { ushort4 u4; __hip_bfloat16 h[4]; } pk;
                #pragma unroll
                for (int r = 0; r < 4; ++r) {
                    float v = acc[m][n][r] + bv;
                    if (relu) v = fmaxf(v, 0.f);
                    pk.h[r] = __float2bfloat16(v);
                }
                size_t off = ((size_t)((rowb >> 5) * 16 + (col >> 4)) << 9)
                           + (size_t)(((rowb >> 3) & 3) * 16 + (col & 15)) * 8
                           + (rowb & 7);
                *(ushort4*)((__hip_bfloat16*)C + off) = pk.u4;
            } else {
                #pragma unroll
                for (int r = 0; r < 4; ++r) {
                    float v = acc[m][n][r] + bv;
                    if (relu) v = fmaxf(v, 0.f);
                    const size_t idx = (size_t)(rowb + r) * N + col;
                    if (resf) v += resf[idx];
                    if (resb) v += __bfloat162float(resb[idx]);
                    if (outmode == 0) ((float*)C)[idx] = v;
                    else ((__hip_bfloat16*)C)[idx] = __float2bfloat16(v);
                }
            }
        }
    }
}

// ============ fused QK + V projection: grid (64, 6); y<4 -> QK, y>=4 -> V ============
__global__ __launch_bounds__(256) void gemm_qkv(
    const __hip_bfloat16* __restrict__ xb,
    const __hip_bfloat16* __restrict__ wqkt2, const __hip_bfloat16* __restrict__ wvt2,
    const float* __restrict__ bqk2, const float* __restrict__ bv,
    __hip_bfloat16* __restrict__ qkb, __hip_bfloat16* __restrict__ vf, int l)
{
    const __hip_bfloat16* Bt;
    const float* bias;
    void* C;
    int N, outmode, by;
    if (blockIdx.y < 4) {
        Bt = wqkt2 + (size_t)l * 131072; bias = bqk2 + l * 512;
        C = qkb; N = 512; outmode = 1; by = blockIdx.y;
    } else {
        Bt = wvt2 + (size_t)l * 65536; bias = bv + l * D_;
        C = vf; N = D_; outmode = 3; by = blockIdx.y - 4;
    }
    gemm_body<64, 128>(xb, Bt, bias, nullptr, nullptr, C, NSQ, N, D_, 0, outmode,
                       blockIdx.x, by);
}

// ===== fused combine + proj GEMM + LayerNorm: 16 complete rows/block, grid 256 =====
// phase 0: split-K combine (po/pm/pl) -> ctx[16][256] bf16 written to static LDS A
//          (swizzled layout matching the MFMA A-read; write-side == read-side).
// phase 1: y = ctx @ wdt^T + bd (A static in LDS, B double-buffered).
// phase 2: in-block LN(y + res); fin=0 -> x/xb, fin=1 -> feats scatter.
__global__ __launch_bounds__(256) void projln_k(
    const __hip_bfloat16* __restrict__ po, const float* __restrict__ pm,
    const float* __restrict__ pl,
    const __hip_bfloat16* __restrict__ wdt,
    const float* __restrict__ bd, const float* __restrict__ resf,
    const float* __restrict__ g, const float* __restrict__ b,
    float* __restrict__ xo, __hip_bfloat16* __restrict__ xob,
    __hip_bfloat16* __restrict__ feats, int fin)
{
    constexpr int KS = 8;
    __shared__ __hip_bfloat16 smA[4][16 * 64];     // 8KB: full ctx[16][256], 4 k-tiles
    __shared__ __hip_bfloat16 smB[2][256 * 64];    // 2 x 32KB
    __shared__ float yl[16][260];                  // pad -> 2-way aliasing only

    const int t = threadIdx.x;
    const int lane = t & 63, wave = t >> 6;
    const int ln = lane & 15, lg = lane >> 4;
    const int row0 = blockIdx.x * 16;

    int boff[8];
    #pragma unroll
    for (int c = 0; c < 8; ++c) {
        int e = c * 256 + t;
        int row = e >> 3, slot = e & 7;
        boff[c] = row * D_ + (slot ^ (row & 7)) * 8;
    }

    auto STAGEB = [&](int k0, int buf) {
        #pragma unroll
        for (int c = 0; c < 8; ++c)
            gload_lds16(wdt + k0 + boff[c], (char*)&smB[buf][0] + (c * 256 + t) * 16);
    };

    STAGEB(0, 0);   // B tile 0 in flight; combine below overlaps its latency

    // ---- phase 0: combine. 2 u16x8 units/thread; 16 rows x 32 units ----
    #pragma unroll
    for (int h = 0; h < 2; ++h) {
        const int u = h * 256 + t;
        const int row = u >> 5, col8 = u & 31;
        const int grow = row0 + row;
        float m[KS], ms = -1e30f;
        #pragma unroll
        for (int s = 0; s < KS; ++s) { m[s] = pm[s * NSQ + grow]; ms = fmaxf(ms, m[s]); }
        float l2 = 0.f, w[KS];
        #pragma unroll
        for (int s = 0; s < KS; ++s) {
            w[s] = __expf(m[s] - ms);
            l2 += w[s] * pl[s * NSQ + grow];
        }
        const float inv = 1.f / l2;
        float num[8];
        #pragma unroll
        for (int j = 0; j < 8; ++j) num[j] = 0.f;
        #pragma unroll
        for (int s = 0; s < KS; ++s) {
            u16x8 v = *(const u16x8*)(po + ((size_t)s * NSQ + grow) * D_ + col8 * 8);
            #pragma unroll
            for (int j = 0; j < 8; ++j) {
                union { float f; unsigned uu; } cv;
                cv.uu = (unsigned)v[j] << 16;
                num[j] += w[s] * cv.f;
            }
        }
        union { u16x8 u8; __hip_bfloat16 hh[8]; } pk;
        #pragma unroll
        for (int j = 0; j < 8; ++j) pk.hh[j] = __float2bfloat16(num[j] * inv);
        // swizzled A write: global slot (col8&7) of row -> LDS slot (col8&7)^(row&7)
        char* dst = (char*)&smA[col8 >> 3][0] + row * 128 +
                    (((col8 & 7) ^ (row & 7)) << 4);
        *(u16x8*)dst = pk.u8;
    }
    __syncthreads();   // drains ds_writes AND B-stage vmcnt

    // ---- phase 1: GEMM over 4 k-tiles; A static, B double-buffered ----
    f32x4 acc[4];
    #pragma unroll
    for (int n = 0; n < 4; ++n) acc[n] = f32x4{0.f, 0.f, 0.f, 0.f};

    int cur = 0;
    for (int kt = 0; kt < 4; ++kt) {
        if (kt + 1 < 4) STAGEB((kt + 1) * 64, cur ^ 1);
        #pragma unroll
        for (int kh = 0; kh < 2; ++kh) {
            bf16x8 af = *(const bf16x8*)((const char*)&smA[kt][0] +
                         ln * 128 + (((kh * 4 + lg) ^ (ln & 7)) << 4));
            #pragma unroll
            for (int n = 0; n < 4; ++n) {
                const int row = wave * 64 + n * 16 + ln;
                bf16x8 bf_ = *(const bf16x8*)((const char*)&smB[cur][0] +
                              row * 128 + (((kh * 4 + lg) ^ (row & 7)) << 4));
                acc[n] = __builtin_amdgcn_mfma_f32_16x16x32_bf16(af, bf_, acc[n], 0, 0, 0);
            }
        }
        __syncthreads();
        cur ^= 1;
    }

    // stash y (GEMM + bias) to LDS
    #pragma unroll
    for (int n = 0; n < 4; ++n) {
        const int col = wave * 64 + n * 16 + ln;
        const float bv = bd[col];
        #pragma unroll
        for (int r = 0; r < 4; ++r)
            yl[lg * 4 + r][col] = acc[n][r] + bv;
    }
    __syncthreads();

    // ---- phase 2: LN; wave handles rows wave*4 .. wave*4+3 ----
    for (int i = 0; i < 4; ++i) {
        const int lrow = wave * 4 + i;
        const int row = row0 + lrow;
        float4 yv = *(const float4*)&yl[lrow][lane * 4];
        float4 rv = *(const float4*)(resf + (size_t)row * D_ + lane * 4);
        float vx = yv.x + rv.x, vy = yv.y + rv.y, vz = yv.z + rv.z, vw = yv.w + rv.w;
        float s = vx + vy + vz + vw;
        #pragma unroll
        for (int off = 1; off < 64; off <<= 1) s += __shfl_xor(s, off);
        float mu = s * (1.f / D_);
        float dx = vx - mu, dy = vy - mu, dz = vz - mu, dw = vw - mu;
        float q = dx * dx + dy * dy + dz * dz + dw * dw;
        #pragma unroll
        for (int off = 1; off < 64; off <<= 1) q += __shfl_xor(q, off);
        float inv = rsqrtf(q * (1.f / D_) + LN_EPS_);
        float4 gg = *(const float4*)(g + lane * 4);
        float4 bb = *(const float4*)(b + lane * 4);
        float4 o;
        o.x = dx * inv * gg.x + bb.x;
        o.y = dy * inv * gg.y + bb.y;
        o.z = dz * inv * gg.z + bb.z;
        o.w = dw * inv * gg.w + bb.w;
        union { ushort4 u4; __hip_bfloat16 h[4]; } pk;
        pk.h[0] = __float2bfloat16(o.x); pk.h[1] = __float2bfloat16(o.y);
        pk.h[2] = __float2bfloat16(o.z); pk.h[3] = __float2bfloat16(o.w);
        if (!fin) {
            *(float4*)(xo + (size_t)row * D_ + lane * 4) = o;
            *(ushort4*)(xob + (size_t)row * D_ + lane * 4) = pk.u4;
        } else {
            const int r = row >> 6, c = row & 63;
            if (r < 63 && c < 63)
                *(ushort4*)(feats + (size_t)(r * 63 + c) * 1024 + lane * 4) = pk.u4;
            if (r < 63 && c > 0)
                *(ushort4*)(feats + (size_t)(r * 63 + c - 1) * 1024 + 256 + lane * 4) = pk.u4;
            if (r > 0 && c < 63)
                *(ushort4*)(feats + (size_t)((r - 1) * 63 + c) * 1024 + 512 + lane * 4) = pk.u4;
            if (r > 0 && c > 0)
                *(ushort4*)(feats + (size_t)((r - 1) * 63 + c - 1) * 1024 + 768 + lane * 4) = pk.u4;
        }
    }
}

// ======= pipelined 128x128 MLP GEMM, BK=64: 256 thr / 4 waves (64x64 per wave) =======
__global__ __launch_bounds__(256, 2) void gemm_128p(
    const __hip_bfloat16* __restrict__ A, const __hip_bfloat16* __restrict__ Bt,
    const float* __restrict__ bias, const __hip_bfloat16* __restrict__ resb,
    __hip_bfloat16* __restrict__ C, int M, int N, int K, int relu)
{
    __shared__ __hip_bfloat16 sm[3][16384];   // 3 bufs x (A 128x64 | B 128x64) = 96KB

    const int t = threadIdx.x;
    const int lane = t & 63, wave = t >> 6;
    const int ln = lane & 15, lg = lane >> 4;
    const int wr = wave >> 1, wc = wave & 1;
    const int row0 = blockIdx.x * 128, col0 = blockIdx.y * 128;

    int aoff[4];
    #pragma unroll
    for (int c = 0; c < 4; ++c) {
        int e = c * 256 + t;
        int row = e >> 3, slot = e & 7;
        int kg = slot ^ (row & 7);
        aoff[c] = row * K + kg * 8;
    }

    const __hip_bfloat16* Ab = A + (size_t)row0 * K;
    const __hip_bfloat16* Bb = Bt + (size_t)col0 * K;

    f32x4 acc[4][4];
    #pragma unroll
    for (int m = 0; m < 4; ++m)
        #pragma unroll
        for (int n = 0; n < 4; ++n) acc[m][n] = f32x4{0.f, 0.f, 0.f, 0.f};

    auto STAGE = [&](int tile, int buf) {
        const int k0 = tile * 64;
        #pragma unroll
        for (int c = 0; c < 4; ++c) {
            gload_lds16(Ab + k0 + aoff[c], (char*)&sm[buf][0] + (c * 256 + t) * 16);
            gload_lds16(Bb + k0 + aoff[c], (char*)&sm[buf][8192] + (c * 256 + t) * 16);
        }
    };

    const int NT = K >> 6;
    STAGE(0, 0); STAGE(1, 1);

    int buf = 0;
    for (int tt = 0; tt < NT; ++tt) {
        const int rem = NT - 1 - tt;
        if (rem >= 1) asm volatile("s_waitcnt vmcnt(8)" ::: "memory");
        else          asm volatile("s_waitcnt vmcnt(0)" ::: "memory");
        __builtin_amdgcn_sched_barrier(0);
        __builtin_amdgcn_s_barrier();
        if (tt + 2 < NT) STAGE(tt + 2, (buf + 2 >= 3) ? buf - 1 : buf + 2);

        const char* base = (const char*)&sm[buf][0];
        #pragma unroll
        for (int kh = 0; kh < 2; ++kh) {
            bf16x8 af[4], bfr[4];
            #pragma unroll
            for (int m = 0; m < 4; ++m) {
                const int row = wr * 64 + m * 16 + ln;
                af[m] = *(const bf16x8*)(base + row * 128 +
                         (((kh * 4 + lg) ^ (row & 7)) << 4));
            }
            #pragma unroll
            for (int n = 0; n < 4; ++n) {
                const int row = wc * 64 + n * 16 + ln;
                bfr[n] = *(const bf16x8*)(base + 16384 + row * 128 +
                          (((kh * 4 + lg) ^ (row & 7)) << 4));
            }
            #pragma unroll
            for (int m = 0; m < 4; ++m)
                #pragma unroll
                for (int n = 0; n < 4; ++n)
                    acc[m][n] = __builtin_amdgcn_mfma_f32_16x16x32_bf16(
                        af[m], bfr[n], acc[m][n], 0, 0, 0);
        }
        buf = (buf + 1 >= 3) ? 0 : buf + 1;
    }

    #pragma unroll
    for (int m = 0; m < 4; ++m) {
        const int rowb = row0 + wr * 64 + m * 16 + lg * 4;
        #pragma unroll
        for (int n = 0; n < 4; ++n) {
            const int col = col0 + wc * 64 + n * 16 + ln;
            const float bv = bias[col];
            #pragma unroll
            for (int r = 0; r < 4; ++r) {
                float v = acc[m][n][r] + bv;
                if (relu) v = fmaxf(v, 0.f);
                const size_t idx = (size_t)(rowb + r) * N + col;
                if (resb) v += __bfloat162float(resb[idx]);
                C[idx] = __float2bfloat16(v);
            }
        }
    }
}

// ========= small-N GEMM fused with softmax+belief+R0 energy (N=16) =========
__global__ __launch_bounds__(256) void gemm_n16b(
    const __hip_bfloat16* __restrict__ A, const __hip_bfloat16* __restrict__ Bt,
    const float* __restrict__ bias, const float* __restrict__ lphi0,
    float* __restrict__ beliefs, float* __restrict__ out, int M, int K)
{
    const int t = threadIdx.x, lane = t & 63, wave = t >> 6;
    const int ln = lane & 15, lg = lane >> 4;
    const int r0 = blockIdx.x * 64 + wave * 16;
    f32x4 acc = {0.f, 0.f, 0.f, 0.f};
    for (int k0 = 0; k0 < K; k0 += 32) {
        bf16x8 a = *(const bf16x8*)(A + (size_t)(r0 + ln) * K + k0 + lg * 8);
        bf16x8 b = *(const bf16x8*)(Bt + (size_t)ln * K + k0 + lg * 8);
        acc = __builtin_amdgcn_mfma_f32_16x16x32_bf16(a, b, acc, 0, 0, 0);
    }
    float e = 0.f;
    #pragma unroll
    for (int r = 0; r < 4; ++r) {
        const int row = r0 + lg * 4 + r;
        float v = acc[r] + bias[ln];
        float mx = v;
        mx = fmaxf(mx, __shfl_xor(mx, 1));
        mx = fmaxf(mx, __shfl_xor(mx, 2));
        mx = fmaxf(mx, __shfl_xor(mx, 4));
        mx = fmaxf(mx, __shfl_xor(mx, 8));
        float ex = __expf(v - mx);
        float s = ex;
        s += __shfl_xor(s, 1);
        s += __shfl_xor(s, 2);
        s += __shfl_xor(s, 4);
        s += __shfl_xor(s, 8);
        if (row < R0_) {
            float bb = ex / s;
            beliefs[(size_t)row * 16 + ln] = bb;
            float bc = fmaxf(bb, CLAMP_);
            e += bc * (logf(bc) - lphi0[(size_t)row * 16 + ln]);
        }
    }
    #pragma unroll
    for (int off = 32; off; off >>= 1) e += __shfl_down(e, off);
    if (lane == 0) atomicAdd(&out[0], e);
}

// ====== fused prep (5700 blocks): castb | owt | attn-wt8 | catbias2 | mlp-wt4 ======
__global__ __launch_bounds__(256) void prep_k(
    const float* __restrict__ node_emb, __hip_bfloat16* __restrict__ xb,
    const float* __restrict__ outw, __hip_bfloat16* __restrict__ outwt,
    const float* __restrict__ Wq, const float* __restrict__ Wk,
    const float* __restrict__ Wv, const float* __restrict__ Wd,
    __hip_bfloat16* __restrict__ wqkt2, __hip_bfloat16* __restrict__ wvt2,
    __hip_bfloat16* __restrict__ wdt2,
    const float* __restrict__ bq, const float* __restrict__ bk,
    float* __restrict__ bqk2,
    const float* __restrict__ M0, const float* __restrict__ M1,
    const float* __restrict__ M2, const float* __restrict__ M3,
    __hip_bfloat16* __restrict__ T0, __hip_bfloat16* __restrict__ T1,
    __hip_bfloat16* __restrict__ T2, __hip_bfloat16* __restrict__ T3,
    float* __restrict__ outp)
{
    __shared__ float tile[32][33];
    const int b = blockIdx.x, t = threadIdx.x;
    if (b == 0 && t < 2) outp[t] = 0.f;
    if (b < 1024) {
        int p = b * 256 + t;
        float4 v = *(const float4*)(node_emb + (size_t)p * 4);
        union { ushort4 u4; __hip_bfloat16 h[4]; } pk;
        pk.h[0] = __float2bfloat16(v.x); pk.h[1] = __float2bfloat16(v.y);
        pk.h[2] = __float2bfloat16(v.z); pk.h[3] = __float2bfloat16(v.w);
        *(ushort4*)(xb + (size_t)p * 4) = pk.u4;
    } else if (b < 1088) {
        int i = (b - 1024) * 256 + t;
        int n = i >> 10, k = i & 1023;
        outwt[i] = __float2bfloat16(outw[k * 16 + n]);
    } else if (b < 1600) {
        int idx = b - 1088;
        int z = idx >> 6, bx = (idx >> 3) & 7, by = idx & 7;
        int l = z >> 2, w = z & 3;
        const float* W = (w == 0 ? Wq : w == 1 ? Wk : w == 2 ? Wv : Wd) + (size_t)l * 65536;
        __hip_bfloat16* Wt = w == 0 ? wqkt2 + (size_t)l * 131072
                           : w == 1 ? wqkt2 + (size_t)l * 131072 + 65536
                           : w == 2 ? wvt2 + (size_t)l * 65536
                                    : wdt2 + (size_t)l * 65536;
        int k0 = bx * 32, n0 = by * 32;
        int r = t >> 3, c4 = (t & 7) * 4;
        float4 v = *(const float4*)(W + (size_t)(k0 + r) * 256 + n0 + c4);
        tile[r][c4 + 0] = v.x; tile[r][c4 + 1] = v.y;
        tile[r][c4 + 2] = v.z; tile[r][c4 + 3] = v.w;
        __syncthreads();
        union { ushort4 u4; __hip_bfloat16 h[4]; } pk;
        #pragma unroll
        for (int i = 0; i < 4; ++i) pk.h[i] = __float2bfloat16(tile[c4 + i][r]);
        *(ushort4*)(Wt + (size_t)(n0 + r) * 256 + k0 + c4) = pk.u4;
    } else if (b < 1604) {
        int idx = (b - 1600) * 256 + t;
        int l = idx >> 9, j = idx & 511;
        bqk2[idx] = j < 256 ? bq[l * 256 + j] : bk[l * 256 + j - 256];
    } else {
        int idx = b - 1604;
        int z = idx >> 10, rem = idx & 1023;
        const float* W = z == 0 ? M0 : z == 1 ? M1 : z == 2 ? M2 : M3;
        __hip_bfloat16* Wt = z == 0 ? T0 : z == 1 ? T1 : z == 2 ? T2 : T3;
        int k0 = (rem >> 5) * 32, n0 = (rem & 31) * 32;
        int r = t >> 3, c4 = (t & 7) * 4;
        float4 v = *(const float4*)(W + (size_t)(k0 + r) * 1024 + n0 + c4);
        tile[r][c4 + 0] = v.x; tile[r][c4 + 1] = v.y;
        tile[r][c4 + 2] = v.z; tile[r][c4 + 3] = v.w;
        __syncthreads();
        union { ushort4 u4; __hip_bfloat16 h[4]; } pk;
        #pragma unroll
        for (int i = 0; i < 4; ++i) pk.h[i] = __float2bfloat16(tile[c4 + i][r]);
        *(ushort4*)(Wt + (size_t)(n0 + r) * 1024 + k0 + c4) = pk.u4;
    }
}

// ============ flash attention: 8 waves, TK=64, counted vmcnt =============
template<int KS>
__global__ __launch_bounds__(512, 2) void attn_mfma_t(
    const __hip_bfloat16* __restrict__ qk, const __hip_bfloat16* __restrict__ vf,
    __hip_bfloat16* __restrict__ po, float* __restrict__ pm, float* __restrict__ pl)
{
    constexpr int KRANGE = NSQ / KS;
    constexpr int NT = KRANGE / TK_;
    constexpr int VOFF = 65536;
    constexpr int POFF = 98304;
    const int t = threadIdx.x;
    const int wave = t >> 6, lane = t & 63;
    const int ln = lane & 15, lg = lane >> 4;
    const int q0 = blockIdx.x * 128 + wave * 16;
    const int ks = blockIdx.y;
    const int k0 = ks * KRANGE;

    __shared__ __align__(16) char smem[116736];

    bf16x8 qa[8];
    #pragma unroll
    for (int s = 0; s < 8; ++s)
        qa[s] = *(const bf16x8*)(qk + (size_t)(q0 + ln) * 512 + s * 32 + lg * 8);

    int srcoff[4];
    #pragma unroll
    for (int c = 0; c < 4; ++c) {
        int row = c * 16 + (t >> 5);
        int g = (t & 31) ^ ((row & 15) << 1);
        srcoff[c] = row * 512 + 256 + g * 8;
    }
    int rb[8];
    #pragma unroll
    for (int s8 = 0; s8 < 8; ++s8)
        rb[s8] = ln * 512 + (((s8 * 4 + lg) ^ (ln << 1)) << 4);

    f32x4 o[16];
    #pragma unroll
    for (int nt = 0; nt < 16; ++nt) o[nt] = f32x4{0.f, 0.f, 0.f, 0.f};
    float rm = -1e30f, rl = 0.f;

    {
        const __hip_bfloat16* src = qk + (size_t)k0 * 512;
        #pragma unroll
        for (int c = 0; c < 4; ++c)
            gload_lds16(src + srcoff[c], smem + c * 8192 + t * 16);
    }
    __syncthreads();

    for (int it = 0; it < NT; ++it) {
        const int cur = it & 1;
        {
            const __hip_bfloat16* vsrc = vf + ((size_t)((k0 + it * TK_) >> 5) << 13);
            #pragma unroll
            for (int c = 0; c < 4; ++c) {
                int idx = c * 512 + t;
                gload_lds16(vsrc + (size_t)idx * 8, smem + VOFF + idx * 16);
            }
        }
        {
            const int itn = (it + 1 < NT) ? it + 1 : it;
            const __hip_bfloat16* src = qk + (size_t)(k0 + itn * TK_) * 512;
            #pragma unroll
            for (int c = 0; c < 4; ++c)
                gload_lds16(src + srcoff[c], smem + (cur ^ 1) * 32768 + c * 8192 + t * 16);
        }
        const char* kbase = smem + cur * 32768;
        f32x4 s4[4];
        #pragma unroll
        for (int nt = 0; nt < 4; ++nt) {
            f32x4 acc = {0.f, 0.f, 0.f, 0.f};
            #pragma unroll
            for (int s8 = 0; s8 < 8; ++s8) {
                bf16x8 kb = *(const bf16x8*)(kbase + nt * 8192 + rb[s8]);
                acc = __builtin_amdgcn_mfma_f32_16x16x32_bf16(kb, qa[s8], acc, 0, 0, 0);
            }
            s4[nt] = acc;
        }
        float mx = -1e30f;
        #pragma unroll
        for (int nt = 0; nt < 4; ++nt)
            #pragma unroll
            for (int r = 0; r < 4; ++r) mx = fmaxf(mx, s4[nt][r]);
        mx = fmaxf(mx, __shfl_xor(mx, 16));
        mx = fmaxf(mx, __shfl_xor(mx, 32));
        float sc = 1.f;
        if (__any(mx > rm + 8.f)) {
            float mnew = fmaxf(rm, mx);
            sc = __expf(rm - mnew);
            rm = mnew;
            float scr[4];
            #pragma unroll
            for (int r = 0; r < 4; ++r) scr[r] = __shfl(sc, lg * 4 + r);
            #pragma unroll
            for (int nt = 0; nt < 16; ++nt)
                #pragma unroll
                for (int r = 0; r < 4; ++r) o[nt][r] *= scr[r];
        }
        float rs = 0.f;
        #pragma unroll
        for (int nt = 0; nt < 4; ++nt)
            #pragma unroll
            for (int r = 0; r < 4; ++r) {
                float p = __expf(s4[nt][r] - rm);
                s4[nt][r] = p;
                rs += p;
            }
        rs += __shfl_xor(rs, 16);
        rs += __shfl_xor(rs, 32);
        rl = rl * sc + rs;
        char* prow = smem + POFF + wave * 2304 + ln * 144;
        #pragma unroll
        for (int nt = 0; nt < 4; ++nt) {
            union { ushort4 u4; __hip_bfloat16 h[4]; } pk;
            #pragma unroll
            for (int r = 0; r < 4; ++r) pk.h[r] = __float2bfloat16(s4[nt][r]);
            *(ushort4*)(prow + nt * 32 + lg * 8) = pk.u4;
        }
        asm volatile("s_waitcnt lgkmcnt(0)" ::: "memory");
        __builtin_amdgcn_sched_barrier(0);
        bf16x8 pa0 = *(const bf16x8*)(prow + lg * 16);
        bf16x8 pa1 = *(const bf16x8*)(prow + 64 + lg * 16);
        asm volatile("s_waitcnt vmcnt(4)" ::: "memory");
        __builtin_amdgcn_sched_barrier(0);
        __builtin_amdgcn_s_barrier();
        const char* vl = smem + VOFF;
        #pragma unroll
        for (int ntd = 0; ntd < 16; ++ntd) {
            bf16x8 vb0 = *(const bf16x8*)(vl + ntd * 1024 + lane * 16);
            bf16x8 vb1 = *(const bf16x8*)(vl + 16384 + ntd * 1024 + lane * 16);
            o[ntd] = __builtin_amdgcn_mfma_f32_16x16x32_bf16(pa0, vb0, o[ntd], 0, 0, 0);
            o[ntd] = __builtin_amdgcn_mfma_f32_16x16x32_bf16(pa1, vb1, o[ntd], 0, 0, 0);
        }
        __syncthreads();
    }
    unsigned short* ob = (unsigned short*)(smem + wave * 8448);
    #pragma unroll
    for (int nt = 0; nt < 16; ++nt)
        #pragma unroll
        for (int r = 0; r < 4; ++r) {
            __hip_bfloat16 h = __float2bfloat16(o[nt][r]);
            ob[(lg * 4 + r) * 264 + nt * 16 + ln] = *(unsigned short*)&h;
        }
    asm volatile("s_waitcnt lgkmcnt(0)" ::: "memory");
    __builtin_amdgcn_sched_barrier(0);
    unsigned short* pob = (unsigned short*)po;
    #pragma unroll
    for (int i = 0; i < 8; ++i) {
        int f = i * 64 + lane;
        int row = f >> 5, dc = f & 31;
        u16x8 vv = *(const u16x8*)(ob + row * 264 + dc * 8);
        *(u16x8*)(pob + ((size_t)ks * NSQ + q0 + row) * D_ + dc * 8) = vv;
    }
    if (lane < 16) {
        pm[ks * NSQ + q0 + lane] = rm;
        pl[ks * NSQ + q0 + lane] = rl;
    }
}

// === fused edges + nodes: grid (16,3); y=0 h-edges, y=1 v-edges, y=2 nodes ===
__global__ __launch_bounds__(256) void edge_node_k(
    const float* __restrict__ beliefs, const float* __restrict__ lphih,
    const float* __restrict__ lphiv, const float* __restrict__ lphi2,
    float* __restrict__ out)
{
    const int e = blockIdx.x * 256 + threadIdx.x;
    float el = 0.f, ml = 0.f;
    if (blockIdx.y == 0) {
        if (e < EH_) {
            const float* bA = beliefs + (size_t)e * 16;
            const float* bB = beliefs + (size_t)(e + 63) * 16;
            float s0[4] = {0,0,0,0}, s1[4] = {0,0,0,0};
            #pragma unroll
            for (int ab = 0; ab < 4; ++ab)
                #pragma unroll
                for (int cd = 0; cd < 4; ++cd) {
                    s0[cd] += bA[ab * 4 + cd];
                    s1[ab] += bB[ab * 4 + cd];
                }
            #pragma unroll
            for (int z = 0; z < 4; ++z) {
                float hb = 0.5f * (s0[z] + s1[z]);
                float d0 = s0[z] - hb, d1 = s1[z] - hb;
                ml += d0 * d0 + d1 * d1;
                float bc = fmaxf(hb, CLAMP_);
                el -= bc * (logf(bc) - lphih[e * 4 + z]);
            }
        }
    } else if (blockIdx.y == 1) {
        if (e < EV_) {
            int r = e / 62, c = e % 62 + 1;
            const float* bL = beliefs + (size_t)(r * 63 + c - 1) * 16;
            const float* bR = beliefs + (size_t)(r * 63 + c) * 16;
            float s0[4] = {0,0,0,0}, s1[4] = {0,0,0,0};
            #pragma unroll
            for (int a = 0; a < 2; ++a)
                #pragma unroll
                for (int bq = 0; bq < 2; ++bq)
                    #pragma unroll
                    for (int c2 = 0; c2 < 2; ++c2)
                        #pragma unroll
                        for (int d = 0; d < 2; ++d) {
                            int idx = a * 8 + bq * 4 + c2 * 2 + d;
                            s0[bq * 2 + d]  += bL[idx];
                            s1[a * 2 + c2] += bR[idx];
                        }
            #pragma unroll
            for (int z = 0; z < 4; ++z) {
                float vb = 0.5f * (s0[z] + s1[z]);
                float d0 = s0[z] - vb, d1 = s1[z] - vb;
                ml += d0 * d0 + d1 * d1;
                float bc = fmaxf(vb, CLAMP_);
                el -= bc * (logf(bc) - lphiv[e * 4 + z]);
            }
        }
    } else {
        if (e < NV_) {
            const int hl = (e / 62) * 63 + (e % 62);
            const float* P00 = beliefs + (size_t)hl * 16;
            const float* P01 = beliefs + (size_t)(hl + 1) * 16;
            const float* P10 = beliefs + (size_t)(hl + 63) * 16;
            const float* P11 = beliefs + (size_t)(hl + 64) * 16;
            float hbl[4], hbr[4];
            #pragma unroll
            for (int z = 0; z < 4; ++z) {
                float s0 = P00[z] + P00[4 + z] + P00[8 + z] + P00[12 + z];
                float s1 = P10[4 * z] + P10[4 * z + 1] + P10[4 * z + 2] + P10[4 * z + 3];
                hbl[z] = 0.5f * (s0 + s1);
                float t0 = P01[z] + P01[4 + z] + P01[8 + z] + P01[12 + z];
                float t1 = P11[4 * z] + P11[4 * z + 1] + P11[4 * z + 2] + P11[4 * z + 3];
                hbr[z] = 0.5f * (t0 + t1);
            }
            float vbu[4], vbd[4];
            #pragma unroll
            for (int z = 0; z < 4; ++z) {
                const int bqd = (z >> 1) * 4 + (z & 1);
                const int ac2 = (z >> 1) * 8 + (z & 1) * 2;
                float s0 = P00[bqd] + P00[bqd + 2] + P00[8 + bqd] + P00[8 + bqd + 2];
                float s1 = P01[ac2] + P01[ac2 + 1] + P01[ac2 + 4] + P01[ac2 + 5];
                vbu[z] = 0.5f * (s0 + s1);
                float t0 = P10[bqd] + P10[bqd + 2] + P10[8 + bqd] + P10[8 + bqd + 2];
                float t1 = P11[ac2] + P11[ac2 + 1] + P11[ac2 + 4] + P11[ac2 + 5];
                vbd[z] = 0.5f * (t0 + t1);
            }
            #pragma unroll
            for (int z = 0; z < 2; ++z) {
                float n0 = hbl[z] + hbl[2 + z];
                float n1 = hbr[z * 2] + hbr[z * 2 + 1];
                float n2 = vbu[z] + vbu[2 + z];
                float n3 = vbd[z * 2] + vbd[z * 2 + 1];
                float nb = 0.25f * (n0 + n1 + n2 + n3);
                float d0 = n0 - nb, d1 = n1 - nb, d2 = n2 - nb, d3 = n3 - nb;
                ml += d0 * d0 + d1 * d1 + d2 * d2 + d3 * d3;
                float bc = fmaxf(nb, CLAMP_);
                el += bc * (logf(bc) - lphi2[e * 2 + z]);
            }
        }
    }
    #pragma unroll
    for (int off = 32; off; off >>= 1) { el += __shfl_down(el, off); ml += __shfl_down(ml, off); }
    if ((threadIdx.x & 63) == 0) { atomicAdd(&out[0], el); atomicAdd(&out[1], ml); }
}

// =======================================================================================
extern "C" void kernel_launch(void* const* d_in, const int* in_sizes, int n_in,
                              void* d_out, int out_size, void* d_ws, size_t ws_size,
                              hipStream_t stream)
{
    (void)in_sizes; (void)n_in; (void)out_size; (void)ws_size;
    const float* node_emb = (const float*)d_in[0];
    const float* Wq  = (const float*)d_in[1];
    const float* bq  = (const float*)d_in[2];
    const float* Wk  = (const float*)d_in[3];
    const float* bk  = (const float*)d_in[4];
    const float* Wv  = (const float*)d_in[5];
    const float* bv  = (const float*)d_in[6];
    const float* Wd  = (const float*)d_in[7];
    const float* bd  = (const float*)d_in[8];
    const float* lng = (const float*)d_in[9];
    const float* lnb = (const float*)d_in[10];
    const float* r1w1 = (const float*)d_in[11];
    const float* r1b1 = (const float*)d_in[12];
    const float* r1w2 = (const float*)d_in[13];
    const float* r1b2 = (const float*)d_in[14];
    const float* r2w1 = (const float*)d_in[15];
    const float* r2b1 = (const float*)d_in[16];
    const float* r2w2 = (const float*)d_in[17];
    const float* r2b2 = (const float*)d_in[18];
    const float* outw = (const float*)d_in[19];
    const float* outb = (const float*)d_in[20];
    const float* lphi0 = (const float*)d_in[21];
    const float* lphih = (const float*)d_in[22];
    const float* lphiv = (const float*)d_in[23];
    const float* lphi2 = (const float*)d_in[24];

    float* ws = (float*)d_ws;
    // persistent block (units: floats)
    float* x      = ws;                          // 1,048,576
    __hip_bfloat16* xb = (__hip_bfloat16*)(ws + 1048576);
    float* belief = ws + 1638400;
    __hip_bfloat16* outwt = (__hip_bfloat16*)(ws + 1736704);
    float* arena  = ws + 1744896;

    // phase A (attention) layout inside arena (float offsets)
    __hip_bfloat16* wqkt2 = (__hip_bfloat16*)(arena);                // [2][512][256]
    __hip_bfloat16* wvt2  = (__hip_bfloat16*)(arena + 131072);       // [2][256][256]
    __hip_bfloat16* wdt2  = (__hip_bfloat16*)(arena + 196608);       // [2][256][256]
    float* bqk2 = arena + 262144;                                    // [2][512]
    __hip_bfloat16* qkb = (__hip_bfloat16*)(arena + 263168);         // [4096][512]
    __hip_bfloat16* vf  = (__hip_bfloat16*)(arena + 1311744);        // packed V (2MB)
    float* pm = arena + 2884608;                                     // [8][4096]
    float* pl = arena + 2950144;
    __hip_bfloat16* po = (__hip_bfloat16*)(arena + 3015680);         // 8M bf16 (KSPLIT=8)

    // phase B: feats + MLP weights OUTSIDE arena; hA/hB reuse dead attention arena.
    __hip_bfloat16* feats = (__hip_bfloat16*)(ws + 8954880);         // [4096][1024] bf16
    __hip_bfloat16* w1t = (__hip_bfloat16*)(ws + 11052032);
    __hip_bfloat16* w2t = (__hip_bfloat16*)(ws + 11576320);
    __hip_bfloat16* w3t = (__hip_bfloat16*)(ws + 12100608);
    __hip_bfloat16* w4t = (__hip_bfloat16*)(ws + 12624896);
    __hip_bfloat16* hA  = (__hip_bfloat16*)(arena);
    __hip_bfloat16* hB  = (__hip_bfloat16*)(arena + 2097152);

    float* outp = (float*)d_out;
    dim3 blk(256);
    dim3 blk512(512);
    prep_k<<<dim3(5700), blk, 0, stream>>>(node_emb, xb, outw, outwt,
                                           Wq, Wk, Wv, Wd, wqkt2, wvt2, wdt2,
                                           bq, bk, bqk2,
                                           r1w1, r1w2, r2w1, r2w2,
                                           w1t, w2t, w3t, w4t, outp);

    for (int l = 0; l < NL; ++l) {
        gemm_qkv<<<dim3(64, 6), blk, 0, stream>>>(xb, wqkt2, wvt2, bqk2, bv,
                                                  qkb, vf, l);
        attn_mfma_t<8><<<dim3(NSQ / 128, 8), blk512, 0, stream>>>(qkb, vf, po, pm, pl);
        projln_k<<<dim3(256), blk, 0, stream>>>(
            po, pm, pl, wdt2 + (size_t)l * 65536, bd + l * D_,
            (l == 0 ? node_emb : x), lng + l * D_, lnb + l * D_,
            x, xb, feats, l);
    }

    dim3 gM(NSQ / 128, HID_ / 128);   // (32, 8) = 256 blocks, 1/CU
    gemm_128p<<<gM, blk, 0, stream>>>(feats, w1t, r1b1, nullptr,
                                      hA, NSQ, HID_, HID_, 1);
    gemm_128p<<<gM, blk, 0, stream>>>(hA, w2t, r1b2, feats,
                                      hB, NSQ, HID_, HID_, 1);
    gemm_128p<<<gM, blk, 0, stream>>>(hB, w3t, r2b1, nullptr,
                                      hA, NSQ, HID_, HID_, 1);
    gemm_128p<<<gM, blk, 0, stream>>>(hA, w4t, r2b2, hB,
                                      feats, NSQ, HID_, HID_, 1);

    gemm_n16b<<<dim3(NSQ / 64), blk, 0, stream>>>(feats, outwt, outb, lphi0,
                                                  belief, outp, NSQ, HID_);
    edge_node_k<<<dim3(16, 3), blk, 0, stream>>>(belief, lphih, lphiv, lphi2, outp);
}